// Round 4
// baseline (116174.377 us; speedup 1.0000x reference)
//
#include <hip/hip_runtime.h>
#include <cmath>

#define SEQ  256
#define BATCH 128
#define FEAT 512
#define HID  1024
#define G4   4096
#define BHh  (BATCH*HID)     // 131072
#define NWG  256
#define NTHR 512

typedef __attribute__((ext_vector_type(8))) __bf16 bf16x8;
typedef __attribute__((ext_vector_type(4))) float f32x4;

__device__ __forceinline__ unsigned short bf16_rne(float f) {
  unsigned int u = __float_as_uint(f);
  unsigned int r = u + 0x7FFFu + ((u >> 16) & 1u);
  return (unsigned short)(r >> 16);
}
__device__ __forceinline__ float bf16_tof(unsigned short s) {
  return __uint_as_float(((unsigned int)s) << 16);
}
__device__ __forceinline__ void gload16(const unsigned short* g, unsigned short* l) {
  __builtin_amdgcn_global_load_lds(
      (const __attribute__((address_space(1))) unsigned int*)g,
      (__attribute__((address_space(3))) unsigned int*)l, 16, 0, 0);
}

// ---------------- conversion kernels (once per call) ----------------

__global__ __launch_bounds__(256)
void convert_hilo(const float* __restrict__ src, unsigned short* __restrict__ hi,
                  unsigned short* __restrict__ lo, int n4) {
  for (int i = blockIdx.x*256 + threadIdx.x; i < n4; i += gridDim.x*256) {
    const float4 v = ((const float4*)src)[i];
    ushort4 h, l;
    h.x = bf16_rne(v.x); l.x = bf16_rne(v.x - bf16_tof(h.x));
    h.y = bf16_rne(v.y); l.y = bf16_rne(v.y - bf16_tof(h.y));
    h.z = bf16_rne(v.z); l.z = bf16_rne(v.z - bf16_tof(h.z));
    h.w = bf16_rne(v.w); l.w = bf16_rne(v.w - bf16_tof(h.w));
    ((ushort4*)hi)[i] = h; ((ushort4*)lo)[i] = l;
  }
}

// gate-weight convert with row permutation: orig row r = g*1024+n -> prow = n*4+g
__global__ __launch_bounds__(256)
void conv_perm(const float* __restrict__ src, unsigned short* __restrict__ hi,
               unsigned short* __restrict__ lo, int n4, int ksh) {
  for (int i = blockIdx.x*256 + threadIdx.x; i < n4; i += gridDim.x*256) {
    const float4 v = ((const float4*)src)[i];
    const int row = i >> ksh, cq = i & ((1 << ksh) - 1);
    const int prow = ((row & 1023) << 2) | (row >> 10);
    const int o = (prow << ksh) + cq;
    ushort4 h, l;
    h.x = bf16_rne(v.x); l.x = bf16_rne(v.x - bf16_tof(h.x));
    h.y = bf16_rne(v.y); l.y = bf16_rne(v.y - bf16_tof(h.y));
    h.z = bf16_rne(v.z); l.z = bf16_rne(v.z - bf16_tof(h.z));
    h.w = bf16_rne(v.w); l.w = bf16_rne(v.w - bf16_tof(h.w));
    ((ushort4*)hi)[o] = h; ((ushort4*)lo)[o] = l;
  }
}

__global__ __launch_bounds__(256)
void bias_perm(const float* __restrict__ bih, const float* __restrict__ bhh,
               float* __restrict__ bsum) {
  const int i = blockIdx.x*256 + threadIdx.x;   // 3*4096
  if (i >= 3*G4) return;
  const int l = i >> 12, r = i & 4095;
  const int prow = ((r & 1023) << 2) | (r >> 10);
  bsum[(l << 12) + prow] = bih[i] + bhh[i];
}

// ---------------- device-scope sync helpers ----------------

__device__ __forceinline__ void tile_sync8(unsigned* tk) {
  asm volatile("s_waitcnt vmcnt(0)" ::: "memory");   // drain my stores to L2
  __syncthreads();
  if (threadIdx.x == 0) {
    __hip_atomic_fetch_add(tk, 1u, __ATOMIC_ACQ_REL, __HIP_MEMORY_SCOPE_AGENT);
    while (__hip_atomic_load(tk, __ATOMIC_ACQUIRE, __HIP_MEMORY_SCOPE_AGENT) < 8u)
      __builtin_amdgcn_s_sleep(2);
  }
  __syncthreads();
}
__device__ __forceinline__ void grid_sync(unsigned* ctr) {
  asm volatile("s_waitcnt vmcnt(0)" ::: "memory");
  __syncthreads();
  if (threadIdx.x == 0) {
    __hip_atomic_fetch_add(ctr, 1u, __ATOMIC_ACQ_REL, __HIP_MEMORY_SCOPE_AGENT);
    while (__hip_atomic_load(ctr, __ATOMIC_ACQUIRE, __HIP_MEMORY_SCOPE_AGENT) < (unsigned)NWG)
      __builtin_amdgcn_s_sleep(4);
  }
  __syncthreads();
}

// ---------------- GEMM phase (verbatim round-3 core, slab output) ----------------
// BM=128(full batch) x BN=128 x BK=64, 8 waves, wave tile 64x32 (4x2 16x16x32 frags),
// 3-product hi/lo split, double-buffered LDS + gload_lds + XOR-(row&7) swizzle.
__device__ __forceinline__ void mm_phase(
    unsigned short* lds, int n0, int kstart, int nch,
    const unsigned short* A1h, const unsigned short* A1l, int K1,
    const unsigned short* A2h, const unsigned short* A2l, int K2,
    const unsigned short* W1h, const unsigned short* W1l,
    const unsigned short* W2h, const unsigned short* W2l,
    float* slab)
{
  const int tid = threadIdx.x;
  const int lane = tid & 63, wave = tid >> 6;
  const int wr = wave >> 2, wc = wave & 3;
  const int rl = lane >> 3, cc = lane & 7;
  const int gcol = (cc ^ rl) << 3;

  auto stage = [&](int ch) {
    const int kg = kstart + (ch << 6);
    const unsigned short *pAh, *pAl, *pWh, *pWl; int sA, sW;
    if (kg < K1) { pAh=A1h+kg; pAl=A1l+kg; sA=K1; pWh=W1h+kg; pWl=W1l+kg; sW=K1; }
    else { const int k2 = kg - K1;
           pAh=A2h+k2; pAl=A2l+k2; sA=K2; pWh=W2h+k2; pWl=W2l+k2; sW=K2; }
    unsigned short* const db = lds + ((ch & 1) << 15);
    #pragma unroll
    for (int q = 0; q < 2; ++q) {
      const int r0 = (wave << 4) + (q << 3);
      const int gr = r0 + rl;
      gload16(pAh + (size_t)gr*sA + gcol,       db +         r0*64);
      gload16(pAl + (size_t)gr*sA + gcol,       db +  8192 + r0*64);
      gload16(pWh + (size_t)(n0+gr)*sW + gcol,  db + 16384 + r0*64);
      gload16(pWl + (size_t)(n0+gr)*sW + gcol,  db + 24576 + r0*64);
    }
  };

  f32x4 z4 = {0.f,0.f,0.f,0.f};
  f32x4 acc[4][2] = {{z4,z4},{z4,z4},{z4,z4},{z4,z4}};

  stage(0);
  for (int ch = 0; ch < nch; ++ch) {
    if (ch + 1 < nch) { stage(ch + 1); asm volatile("s_waitcnt vmcnt(8)" ::: "memory"); }
    else             { asm volatile("s_waitcnt vmcnt(0)" ::: "memory"); }
    __builtin_amdgcn_sched_barrier(0);
    __builtin_amdgcn_s_barrier();
    const unsigned short* const cb = lds + ((ch & 1) << 15);
    #pragma unroll
    for (int kh = 0; kh < 2; ++kh) {
      const int j0 = (kh << 2) + (lane >> 4);
      bf16x8 ah[4], al[4], bh[2], bl[2];
      #pragma unroll
      for (int mi = 0; mi < 4; ++mi) {
        const int row = (wr << 6) + (mi << 4) + (lane & 15);
        const int off = row*64 + ((j0 ^ (row & 7)) << 3);
        ah[mi] = *(const bf16x8*)(cb + off);
        al[mi] = *(const bf16x8*)(cb + 8192 + off);
      }
      #pragma unroll
      for (int ni = 0; ni < 2; ++ni) {
        const int wrow = (wc << 5) + (ni << 4) + (lane & 15);
        const int off = wrow*64 + ((j0 ^ (wrow & 7)) << 3);
        bh[ni] = *(const bf16x8*)(cb + 16384 + off);
        bl[ni] = *(const bf16x8*)(cb + 24576 + off);
      }
      #pragma unroll
      for (int mi = 0; mi < 4; ++mi)
        #pragma unroll
        for (int ni = 0; ni < 2; ++ni) {
          acc[mi][ni] = __builtin_amdgcn_mfma_f32_16x16x32_bf16(ah[mi], bh[ni], acc[mi][ni], 0,0,0);
          acc[mi][ni] = __builtin_amdgcn_mfma_f32_16x16x32_bf16(al[mi], bh[ni], acc[mi][ni], 0,0,0);
          acc[mi][ni] = __builtin_amdgcn_mfma_f32_16x16x32_bf16(ah[mi], bl[ni], acc[mi][ni], 0,0,0);
        }
    }
    __builtin_amdgcn_s_barrier();
  }
  // C/D layout: col=lane&15, row=(lane>>4)*4+r  [m89/m91 verified]
  const int rb = (lane >> 4) << 2, cbl = lane & 15;
  #pragma unroll
  for (int mi = 0; mi < 4; ++mi)
    #pragma unroll
    for (int ni = 0; ni < 2; ++ni)
      #pragma unroll
      for (int r = 0; r < 4; ++r) {
        const int row = (wr << 6) + (mi << 4) + rb + r;
        const int col = (wc << 5) + (ni << 4) + cbl;
        slab[(row << 7) + col] = acc[mi][ni][r];
      }
}

// ---------------- cell & linear-reduce phases ----------------

__device__ __forceinline__ void cell_phase(
    int jg, int zg, const float* gpart, const float* bsl,
    const unsigned short* fth, const unsigned short* ftl,
    float* cslot,
    unsigned short* hWh, unsigned short* hWl,
    unsigned short* sh, unsigned short* sl)
{
  const int e = (zg << 9) | threadIdx.x;   // 0..4095 within tile
  const int m = e >> 5, nl = e & 31;
  const int ng = (jg << 5) + nl;
  const float* base = gpart + ((size_t)jg << 17) + (m << 7) + (nl << 2);
  float4 g = {0.f,0.f,0.f,0.f};
  #pragma unroll
  for (int zz = 0; zz < 8; ++zz) {
    const float4 v = *(const float4*)(base + ((size_t)zz << 14));
    g.x += v.x; g.y += v.y; g.z += v.z; g.w += v.w;
  }
  const float4 bs = *(const float4*)(bsl + (ng << 2));
  const float iv = 1.f/(1.f+expf(-(g.x+bs.x)));
  const float fv = 1.f/(1.f+expf(-(g.y+bs.y)));
  const float gv = tanhf(g.z+bs.z);
  const float ov = 1.f/(1.f+expf(-(g.w+bs.w)));
  const float cn = fv * (*cslot) + iv * gv;
  *cslot = cn;
  const float h = ov * tanhf(cn);
  const int idx = (m << 10) + ng;
  const unsigned short hh = bf16_rne(h);
  hWh[idx] = hh; hWl[idx] = bf16_rne(h - bf16_tof(hh));
  float s = h;
  if (fth) s += bf16_tof(fth[idx]) + bf16_tof(ftl[idx]);
  const unsigned short ss = bf16_rne(s);
  sh[idx] = ss; sl[idx] = bf16_rne(s - bf16_tof(ss));
}

__device__ __forceinline__ void ftred_phase(
    int jl, int zl, const float* lpart, const float* bout,
    unsigned short* fth, unsigned short* ftl, float* outp)
{
  const int u = (zl << 9) | threadIdx.x;   // 0..4095
  #pragma unroll
  for (int i = 0; i < 4; ++i) {
    const int e = u + (i << 12);           // 0..16383
    const int m = e >> 7, nc = e & 127;
    const int ng = (jl << 7) + nc;
    float v = bout[ng];
    #pragma unroll
    for (int zz = 0; zz < 8; ++zz)
      v += lpart[(((size_t)(jl*8+zz)) << 14) + (m << 7) + nc];
    const int idx = (m << 10) + ng;
    if (outp) outp[idx] = v;
    else {
      const unsigned short fh = bf16_rne(v);
      fth[idx] = fh; ftl[idx] = bf16_rne(v - bf16_tof(fh));
    }
  }
}

// ---------------- the persistent kernel ----------------

__global__ __launch_bounds__(512, 2)
void fflstm_persist(
    const float* __restrict__ x,
    const unsigned short* __restrict__ Wg_h, const unsigned short* __restrict__ Wg_l,
    const unsigned short* __restrict__ Whh_h, const unsigned short* __restrict__ Whh_l,
    const unsigned short* __restrict__ Wout_h, const unsigned short* __restrict__ Wout_l,
    const float* __restrict__ bsum, const float* __restrict__ bout,
    float* gpart, float* lpart,
    unsigned short* h_h, unsigned short* h_l,
    unsigned short* s_h, unsigned short* s_l,
    unsigned short* ft_h, unsigned short* ft_l,
    unsigned short* xb_h, unsigned short* xb_l,
    unsigned* tkg, unsigned* tkl, unsigned* gbar,
    float* out)
{
  __shared__ unsigned short smem[2*4*128*64];   // 128 KB
  __shared__ float cshr[3*512];                 // per-thread c, 3 layers
  const int b = blockIdx.x, tid = threadIdx.x;
  cshr[tid] = 0.f; cshr[512+tid] = 0.f; cshr[1024+tid] = 0.f;

  const int jg = ((b & 7) << 2) + ((b >> 3) & 3);  // gates tile 0..31 (XCD-grouped)
  const int zg = b >> 5;                            // gates k-slice 0..7
  const int jl = b & 7, zl = b >> 3;                // lin tile/slice (valid b<64)
  int bix = 0;

  // prologue: convert x[0] -> xb[0]
  {
    const int u = (b << 9) | tid;
    if (u < 16384) {
      const float4 v = ((const float4*)x)[u];
      ushort4 h4, l4;
      h4.x=bf16_rne(v.x); l4.x=bf16_rne(v.x-bf16_tof(h4.x));
      h4.y=bf16_rne(v.y); l4.y=bf16_rne(v.y-bf16_tof(h4.y));
      h4.z=bf16_rne(v.z); l4.z=bf16_rne(v.z-bf16_tof(h4.z));
      h4.w=bf16_rne(v.w); l4.w=bf16_rne(v.w-bf16_tof(h4.w));
      ((ushort4*)xb_h)[u] = h4; ((ushort4*)xb_l)[u] = l4;
    }
  }
  grid_sync(gbar + bix++);

  for (int t = 0; t < SEQ; ++t) {
    const int p = t & 1;
    const unsigned short* hR_h = h_h + (size_t)p*3*BHh;
    const unsigned short* hR_l = h_l + (size_t)p*3*BHh;
    unsigned short* hW_h = h_h + (size_t)(1-p)*3*BHh;
    unsigned short* hW_l = h_l + (size_t)(1-p)*3*BHh;

    for (int l = 0; l < 3; ++l) {
      const int K1   = l ? HID : FEAT;
      const int Kper = l ? 256 : 192;
      const int nch  = l ? 4 : 3;
      const unsigned short* A1h = l ? ft_h : (xb_h + p*65536);
      const unsigned short* A1l = l ? ft_l : (xb_l + p*65536);
      const size_t wgo = l ? ((size_t)l*4194304 - 2097152) : 0;

      mm_phase(smem, jg << 7, zg*Kper, nch,
               A1h, A1l, K1,
               hR_h + (size_t)l*BHh, hR_l + (size_t)l*BHh, HID,
               Wg_h + wgo, Wg_l + wgo,
               Whh_h + (size_t)l*4194304, Whh_l + (size_t)l*4194304,
               gpart + ((size_t)(jg*8+zg) << 14));
      tile_sync8(tkg + ((t*3+l) << 5) + jg);
      cell_phase(jg, zg, gpart, bsum + (l << 12),
                 l ? ft_h : nullptr, l ? ft_l : nullptr,
                 &cshr[l*512 + tid],
                 hW_h + (size_t)l*BHh, hW_l + (size_t)l*BHh, s_h, s_l);
      grid_sync(gbar + bix++);

      if (b < 64) {
        mm_phase(smem, jl << 7, zl << 7, 2,
                 s_h, s_l, HID, s_h, s_l, HID,
                 Wout_h, Wout_l, Wout_h, Wout_l,
                 lpart + ((size_t)(jl*8+zl) << 14));
        tile_sync8(tkl + ((t*3+l) << 3) + jl);
        ftred_phase(jl, zl, lpart, bout,
                    (l==2) ? nullptr : ft_h, ft_l,
                    (l==2) ? (out + (size_t)t*BHh) : nullptr);
      } else if (l == 0 && t + 1 < SEQ) {
        // idle WGs convert x[t+1] into the other xb buffer
        const int u = ((b - 64) << 9) | tid;
        if (u < 16384) {
          const float4 v = ((const float4*)x)[(t+1)*16384 + u];
          ushort4 h4, l4;
          h4.x=bf16_rne(v.x); l4.x=bf16_rne(v.x-bf16_tof(h4.x));
          h4.y=bf16_rne(v.y); l4.y=bf16_rne(v.y-bf16_tof(h4.y));
          h4.z=bf16_rne(v.z); l4.z=bf16_rne(v.z-bf16_tof(h4.z));
          h4.w=bf16_rne(v.w); l4.w=bf16_rne(v.w-bf16_tof(h4.w));
          const int q = (t+1) & 1;
          ((ushort4*)(xb_h + q*65536))[u] = h4;
          ((ushort4*)(xb_l + q*65536))[u] = l4;
        }
      }
      grid_sync(gbar + bix++);
    }
  }
}

// ---------------- host ----------------

extern "C" void kernel_launch(void* const* d_in, const int* in_sizes, int n_in,
                              void* d_out, int out_size, void* d_ws, size_t ws_size,
                              hipStream_t stream) {
  const float* x    = (const float*)d_in[0];
  const float* Wih0 = (const float*)d_in[1];
  const float* Wihr = (const float*)d_in[2];
  const float* Whh  = (const float*)d_in[3];
  const float* bih  = (const float*)d_in[4];
  const float* bhh  = (const float*)d_in[5];
  const float* Wout = (const float*)d_in[6];
  const float* bout = (const float*)d_in[7];
  float* out = (float*)d_out;

  char* base = (char*)d_ws;
  size_t off = 0;
  auto alloc = [&](size_t bytes) -> char* {
    char* p = base + off;
    off = (off + bytes + 255) & ~(size_t)255;
    return p;
  };
  float* gpart = (float*)alloc(32ull*8*128*128*4);          // 16.8 MB
  float* lpart = (float*)alloc(8ull*8*128*128*4);           // 4.2 MB
  unsigned short* h_h = (unsigned short*)alloc(2ull*3*BHh*2);
  unsigned short* h_l = (unsigned short*)alloc(2ull*3*BHh*2);
  unsigned short* s_h = (unsigned short*)alloc((size_t)BHh*2);
  unsigned short* s_l = (unsigned short*)alloc((size_t)BHh*2);
  unsigned short* ft_h = (unsigned short*)alloc((size_t)BHh*2);
  unsigned short* ft_l = (unsigned short*)alloc((size_t)BHh*2);
  unsigned short* xb_h = (unsigned short*)alloc(2ull*BATCH*FEAT*2);
  unsigned short* xb_l = (unsigned short*)alloc(2ull*BATCH*FEAT*2);
  float* bsum = (float*)alloc(3ull*G4*4);
  unsigned short* Wg_h  = (unsigned short*)alloc((2097152ull+4194304+4194304)*2);
  unsigned short* Wg_l  = (unsigned short*)alloc((2097152ull+4194304+4194304)*2);
  unsigned short* Whh_h = (unsigned short*)alloc(3ull*4194304*2);
  unsigned short* Whh_l = (unsigned short*)alloc(3ull*4194304*2);
  unsigned short* Wout_h = (unsigned short*)alloc(1048576ull*2);
  unsigned short* Wout_l = (unsigned short*)alloc(1048576ull*2);
  unsigned* tkg  = (unsigned*)alloc(256ull*3*32*4);
  unsigned* tkl  = (unsigned*)alloc(256ull*3*8*4);
  unsigned* gbar = (unsigned*)alloc(2048ull*4);

  // weight conversion (+ gate-row permutation)
  conv_perm<<<2048, 256, 0, stream>>>(Wih0, Wg_h, Wg_l, G4*FEAT/4, 7);
  conv_perm<<<2048, 256, 0, stream>>>(Wihr,              Wg_h + 2097152, Wg_l + 2097152, G4*HID/4, 8);
  conv_perm<<<2048, 256, 0, stream>>>(Wihr + 4194304,    Wg_h + 6291456, Wg_l + 6291456, G4*HID/4, 8);
  for (int l = 0; l < 3; ++l)
    conv_perm<<<2048, 256, 0, stream>>>(Whh + (size_t)l*4194304,
        Whh_h + (size_t)l*4194304, Whh_l + (size_t)l*4194304, G4*HID/4, 8);
  convert_hilo<<<1024, 256, 0, stream>>>(Wout, Wout_h, Wout_l, HID*HID/4);
  bias_perm<<<48, 256, 0, stream>>>(bih, bhh, bsum);

  // zero recurrent state + sync counters each call (replayed in graph)
  hipMemsetAsync(h_h, 0, 2ull*3*BHh*2, stream);
  hipMemsetAsync(h_l, 0, 2ull*3*BHh*2, stream);
  hipMemsetAsync(tkg, 0, 256ull*3*32*4, stream);
  hipMemsetAsync(tkl, 0, 256ull*3*8*4, stream);
  hipMemsetAsync(gbar, 0, 2048ull*4, stream);

  fflstm_persist<<<dim3(NWG), dim3(NTHR), 0, stream>>>(
      x, Wg_h, Wg_l, Whh_h, Whh_l, Wout_h, Wout_l, bsum, bout,
      gpart, lpart, h_h, h_l, s_h, s_l, ft_h, ft_l, xb_h, xb_l,
      tkg, tkl, gbar, out);
}

// Round 5
// 75876.263 us; speedup vs baseline: 1.5311x; 1.5311x over previous
//
#include <hip/hip_runtime.h>
#include <cmath>

#define SEQ  256
#define BATCH 128
#define FEAT 512
#define HID  1024
#define G4   4096
#define BHh  (BATCH*HID)     // 131072
#define NWG  256
#define NTHR 512
#define FLS  32              // flag stride in u32 (128 B line)

typedef __attribute__((ext_vector_type(8))) __bf16 bf16x8;
typedef __attribute__((ext_vector_type(4))) float f32x4;

__device__ __forceinline__ unsigned short bf16_rne(float f) {
  unsigned int u = __float_as_uint(f);
  unsigned int r = u + 0x7FFFu + ((u >> 16) & 1u);
  return (unsigned short)(r >> 16);
}
__device__ __forceinline__ float bf16_tof(unsigned short s) {
  return __uint_as_float(((unsigned int)s) << 16);
}
__device__ __forceinline__ void gload16(const unsigned short* g, unsigned short* l) {
  __builtin_amdgcn_global_load_lds(
      (const __attribute__((address_space(1))) unsigned int*)g,
      (__attribute__((address_space(3))) unsigned int*)l, 16, 0, 0);
}

// ---------------- conversion kernels (once per call) ----------------

__global__ __launch_bounds__(256)
void convert_hilo(const float* __restrict__ src, unsigned short* __restrict__ hi,
                  unsigned short* __restrict__ lo, int n4) {
  for (int i = blockIdx.x*256 + threadIdx.x; i < n4; i += gridDim.x*256) {
    const float4 v = ((const float4*)src)[i];
    ushort4 h, l;
    h.x = bf16_rne(v.x); l.x = bf16_rne(v.x - bf16_tof(h.x));
    h.y = bf16_rne(v.y); l.y = bf16_rne(v.y - bf16_tof(h.y));
    h.z = bf16_rne(v.z); l.z = bf16_rne(v.z - bf16_tof(h.z));
    h.w = bf16_rne(v.w); l.w = bf16_rne(v.w - bf16_tof(h.w));
    ((ushort4*)hi)[i] = h; ((ushort4*)lo)[i] = l;
  }
}

// gate-weight convert with row permutation: orig row r = g*1024+n -> prow = n*4+g
__global__ __launch_bounds__(256)
void conv_perm(const float* __restrict__ src, unsigned short* __restrict__ hi,
               unsigned short* __restrict__ lo, int n4, int ksh) {
  for (int i = blockIdx.x*256 + threadIdx.x; i < n4; i += gridDim.x*256) {
    const float4 v = ((const float4*)src)[i];
    const int row = i >> ksh, cq = i & ((1 << ksh) - 1);
    const int prow = ((row & 1023) << 2) | (row >> 10);
    const int o = (prow << ksh) + cq;
    ushort4 h, l;
    h.x = bf16_rne(v.x); l.x = bf16_rne(v.x - bf16_tof(h.x));
    h.y = bf16_rne(v.y); l.y = bf16_rne(v.y - bf16_tof(h.y));
    h.z = bf16_rne(v.z); l.z = bf16_rne(v.z - bf16_tof(h.z));
    h.w = bf16_rne(v.w); l.w = bf16_rne(v.w - bf16_tof(h.w));
    ((ushort4*)hi)[o] = h; ((ushort4*)lo)[o] = l;
  }
}

__global__ __launch_bounds__(256)
void bias_perm(const float* __restrict__ bih, const float* __restrict__ bhh,
               float* __restrict__ bsum) {
  const int i = blockIdx.x*256 + threadIdx.x;   // 3*4096
  if (i >= 3*G4) return;
  const int l = i >> 12, r = i & 4095;
  const int prow = ((r & 1023) << 2) | (r >> 10);
  bsum[(l << 12) + prow] = bih[i] + bhh[i];
}

// ---------------- flag-based sync (no RMW contention) ----------------
// Each WG release-stores a monotonically increasing generation into its own
// 128B-padded slot; waiters poll peer slots with relaxed agent loads (one
// line per lane, parallel), then one acquire fence. Generations never reset
// within a launch; flags memset to 0 once per kernel_launch.

__device__ __forceinline__ void sync_grid(unsigned* gf, unsigned gen, int b) {
  __syncthreads();                              // drains each wave's vmem
  if (threadIdx.x == 0)
    __hip_atomic_store(&gf[b*FLS], gen, __ATOMIC_RELEASE, __HIP_MEMORY_SCOPE_AGENT);
  if (threadIdx.x < NWG) {
    while (__hip_atomic_load(&gf[threadIdx.x*FLS], __ATOMIC_RELAXED,
                             __HIP_MEMORY_SCOPE_AGENT) < gen)
      __builtin_amdgcn_s_sleep(1);
  }
  __builtin_amdgcn_fence(__ATOMIC_ACQUIRE, "agent");
  __syncthreads();
}

__device__ __forceinline__ void sync_tile(unsigned* tf, unsigned gen, int b,
                                          int peer0, int pstride, int npeer) {
  __syncthreads();
  if (threadIdx.x == 0)
    __hip_atomic_store(&tf[b*FLS], gen, __ATOMIC_RELEASE, __HIP_MEMORY_SCOPE_AGENT);
  if ((int)threadIdx.x < npeer) {
    const int pb = peer0 + (int)threadIdx.x * pstride;
    while (__hip_atomic_load(&tf[pb*FLS], __ATOMIC_RELAXED,
                             __HIP_MEMORY_SCOPE_AGENT) < gen)
      __builtin_amdgcn_s_sleep(1);
  }
  __builtin_amdgcn_fence(__ATOMIC_ACQUIRE, "agent");
  __syncthreads();
}

// ---------------- GEMM phase (round-3/4 core, MFR-templated) ----------------
// BM = MFR*32 rows x BN=128 x BK=64, 8 waves (2 wr x 4 wc), wave tile
// (MFR*16) x 32 = MFR x 2 frags of 16x16x32, 3-product hi/lo split,
// double-buffered LDS + gload_lds + XOR-(row&7) swizzle.
template<int MFR>
__device__ __forceinline__ void mm_phase(
    unsigned short* lds, int n0, int kstart, int nch,
    const unsigned short* A1h, const unsigned short* A1l, int K1,
    const unsigned short* A2h, const unsigned short* A2l, int K2,
    const unsigned short* W1h, const unsigned short* W1l,
    const unsigned short* W2h, const unsigned short* W2l,
    float* slab)
{
  const int tid = threadIdx.x;
  const int lane = tid & 63, wave = tid >> 6;
  const int wr = wave >> 2, wc = wave & 3;
  const int rl = lane >> 3, cc = lane & 7;
  const int gcol = (cc ^ rl) << 3;

  auto stage = [&](int ch) {
    const int kg = kstart + (ch << 6);
    const unsigned short *pAh, *pAl, *pWh, *pWl; int sA, sW;
    if (kg < K1) { pAh=A1h+kg; pAl=A1l+kg; sA=K1; pWh=W1h+kg; pWl=W1l+kg; sW=K1; }
    else { const int k2 = kg - K1;
           pAh=A2h+k2; pAl=A2l+k2; sA=K2; pWh=W2h+k2; pWl=W2l+k2; sW=K2; }
    unsigned short* const db = lds + ((ch & 1) << 15);
    #pragma unroll
    for (int q = 0; q < MFR/2; ++q) {           // A rows: MFR*32
      const int r0 = (MFR == 4) ? ((wave << 4) + (q << 3)) : (wave << 3);
      const int gr = r0 + rl;
      gload16(pAh + (size_t)gr*sA + gcol,       db +         r0*64);
      gload16(pAl + (size_t)gr*sA + gcol,       db +  8192 + r0*64);
    }
    #pragma unroll
    for (int q = 0; q < 2; ++q) {               // W rows: 128 always
      const int r0 = (wave << 4) + (q << 3);
      const int gr = r0 + rl;
      gload16(pWh + (size_t)(n0+gr)*sW + gcol,  db + 16384 + r0*64);
      gload16(pWl + (size_t)(n0+gr)*sW + gcol,  db + 24576 + r0*64);
    }
  };

  f32x4 z4 = {0.f,0.f,0.f,0.f};
  f32x4 acc[MFR][2];
  #pragma unroll
  for (int mi = 0; mi < MFR; ++mi) { acc[mi][0] = z4; acc[mi][1] = z4; }

  stage(0);
  for (int ch = 0; ch < nch; ++ch) {
    if (ch + 1 < nch) {
      stage(ch + 1);
      // loads/stage = MFR + 4; wait for current chunk, keep next in flight
      if constexpr (MFR == 4) asm volatile("s_waitcnt vmcnt(8)" ::: "memory");
      else                    asm volatile("s_waitcnt vmcnt(6)" ::: "memory");
    } else {
      asm volatile("s_waitcnt vmcnt(0)" ::: "memory");
    }
    __builtin_amdgcn_sched_barrier(0);
    __builtin_amdgcn_s_barrier();
    const unsigned short* const cb = lds + ((ch & 1) << 15);
    #pragma unroll
    for (int kh = 0; kh < 2; ++kh) {
      const int j0 = (kh << 2) + (lane >> 4);
      bf16x8 ah[MFR], al[MFR], bh[2], bl[2];
      #pragma unroll
      for (int mi = 0; mi < MFR; ++mi) {
        const int row = wr*(MFR*16) + (mi << 4) + (lane & 15);
        const int off = row*64 + ((j0 ^ (row & 7)) << 3);
        ah[mi] = *(const bf16x8*)(cb + off);
        al[mi] = *(const bf16x8*)(cb + 8192 + off);
      }
      #pragma unroll
      for (int ni = 0; ni < 2; ++ni) {
        const int wrow = (wc << 5) + (ni << 4) + (lane & 15);
        const int off = wrow*64 + ((j0 ^ (wrow & 7)) << 3);
        bh[ni] = *(const bf16x8*)(cb + 16384 + off);
        bl[ni] = *(const bf16x8*)(cb + 24576 + off);
      }
      #pragma unroll
      for (int mi = 0; mi < MFR; ++mi)
        #pragma unroll
        for (int ni = 0; ni < 2; ++ni) {
          acc[mi][ni] = __builtin_amdgcn_mfma_f32_16x16x32_bf16(ah[mi], bh[ni], acc[mi][ni], 0,0,0);
          acc[mi][ni] = __builtin_amdgcn_mfma_f32_16x16x32_bf16(al[mi], bh[ni], acc[mi][ni], 0,0,0);
          acc[mi][ni] = __builtin_amdgcn_mfma_f32_16x16x32_bf16(ah[mi], bl[ni], acc[mi][ni], 0,0,0);
        }
    }
    __builtin_amdgcn_s_barrier();
  }
  // C/D layout: col=lane&15, row=(lane>>4)*4+r  [m89/m91 verified]
  const int rb = (lane >> 4) << 2, cbl = lane & 15;
  #pragma unroll
  for (int mi = 0; mi < MFR; ++mi)
    #pragma unroll
    for (int ni = 0; ni < 2; ++ni)
      #pragma unroll
      for (int r = 0; r < 4; ++r) {
        const int row = wr*(MFR*16) + (mi << 4) + rb + r;
        const int col = (wc << 5) + (ni << 4) + cbl;
        slab[(row << 7) + col] = acc[mi][ni][r];
      }
}

// ---------------- cell & linear-reduce phases ----------------

__device__ __forceinline__ void cell_phase(
    int jg, int zg, const float* gpart, const float* bsl,
    const unsigned short* fth, const unsigned short* ftl,
    float* cslot,
    unsigned short* hWh, unsigned short* hWl,
    unsigned short* sh, unsigned short* sl)
{
  const int e = (zg << 9) | threadIdx.x;   // 0..4095 within tile
  const int m = e >> 5, nl = e & 31;
  const int ng = (jg << 5) + nl;
  const float* base = gpart + ((size_t)jg << 17) + (m << 7) + (nl << 2);
  float4 g = {0.f,0.f,0.f,0.f};
  #pragma unroll
  for (int zz = 0; zz < 8; ++zz) {
    const float4 v = *(const float4*)(base + ((size_t)zz << 14));
    g.x += v.x; g.y += v.y; g.z += v.z; g.w += v.w;
  }
  const float4 bs = *(const float4*)(bsl + (ng << 2));
  const float iv = 1.f/(1.f+expf(-(g.x+bs.x)));
  const float fv = 1.f/(1.f+expf(-(g.y+bs.y)));
  const float gv = tanhf(g.z+bs.z);
  const float ov = 1.f/(1.f+expf(-(g.w+bs.w)));
  const float cn = fv * (*cslot) + iv * gv;
  *cslot = cn;
  const float h = ov * tanhf(cn);
  const int idx = (m << 10) + ng;
  const unsigned short hh = bf16_rne(h);
  hWh[idx] = hh; hWl[idx] = bf16_rne(h - bf16_tof(hh));
  float s = h;
  if (fth) s += bf16_tof(fth[idx]) + bf16_tof(ftl[idx]);
  const unsigned short ss = bf16_rne(s);
  sh[idx] = ss; sl[idx] = bf16_rne(s - bf16_tof(ss));
}

// reduce 16 split-K slabs of a 64x128 linear tile (ml, jl)
__device__ __forceinline__ void ftred_phase(
    int ml, int jl, int zl, const float* lpart, const float* bout,
    unsigned short* fth, unsigned short* ftl, float* outp)
{
  const int e = (zl << 9) | threadIdx.x;         // 0..8191 within tile
  const int m = (ml << 6) + (e >> 7), nc = e & 127;
  const int ng = (jl << 7) + nc;
  float v = bout[ng];
  const float* bs = lpart + ((size_t)((ml << 7) | (jl << 4)) << 13) + e;
  #pragma unroll
  for (int z = 0; z < 16; ++z) v += bs[(size_t)z << 13];
  const int idx = (m << 10) + ng;
  if (outp) outp[idx] = v;
  else {
    const unsigned short fh = bf16_rne(v);
    fth[idx] = fh; ftl[idx] = bf16_rne(v - bf16_tof(fh));
  }
}

// ---------------- the persistent kernel ----------------

__global__ __launch_bounds__(512, 2)
void fflstm_persist(
    const float* __restrict__ x,
    const unsigned short* __restrict__ Wg_h, const unsigned short* __restrict__ Wg_l,
    const unsigned short* __restrict__ Whh_h, const unsigned short* __restrict__ Whh_l,
    const unsigned short* __restrict__ Wout_h, const unsigned short* __restrict__ Wout_l,
    const float* __restrict__ bsum, const float* __restrict__ bout,
    float* gpart, float* lpart,
    unsigned short* h_h, unsigned short* h_l,
    unsigned short* s_h, unsigned short* s_l,
    unsigned short* ft_h, unsigned short* ft_l,
    unsigned short* xb_h, unsigned short* xb_l,
    unsigned* fG, unsigned* fTG, unsigned* fTL,
    float* out)
{
  __shared__ unsigned short smem[2*4*128*64];   // 128 KB
  __shared__ float cshr[3*512];                 // per-thread c, 3 layers
  const int b = blockIdx.x, tid = threadIdx.x;
  cshr[tid] = 0.f; cshr[512+tid] = 0.f; cshr[1024+tid] = 0.f;

  const int jg = ((b & 7) << 2) + ((b >> 3) & 3);  // gates tile 0..31 (XCD-grouped)
  const int zg = b >> 5;                            // gates k-slice 0..7
  const int gpeer0 = (jg >> 2) | ((jg & 3) << 3);   // peer WG base for this jg
  const int ml = b >> 7, jl = (b >> 4) & 7, zl = b & 15;  // lin m-block/tile/slice
  const int lpeer0 = (ml << 7) | (jl << 4);
  unsigned ggen = 0;

  // prologue: convert x[0] -> xb slot 0
  {
    const int u = (b << 9) | tid;
    if (u < 16384) {
      const float4 v = ((const float4*)x)[u];
      ushort4 h4, l4;
      h4.x=bf16_rne(v.x); l4.x=bf16_rne(v.x-bf16_tof(h4.x));
      h4.y=bf16_rne(v.y); l4.y=bf16_rne(v.y-bf16_tof(h4.y));
      h4.z=bf16_rne(v.z); l4.z=bf16_rne(v.z-bf16_tof(h4.z));
      h4.w=bf16_rne(v.w); l4.w=bf16_rne(v.w-bf16_tof(h4.w));
      ((ushort4*)xb_h)[u] = h4; ((ushort4*)xb_l)[u] = l4;
    }
  }
  sync_grid(fG, ++ggen, b);

  for (int t = 0; t < SEQ; ++t) {
    const int p = t & 1;
    const unsigned short* hR_h = h_h + (size_t)p*3*BHh;
    const unsigned short* hR_l = h_l + (size_t)p*3*BHh;
    unsigned short* hW_h = h_h + (size_t)(1-p)*3*BHh;
    unsigned short* hW_l = h_l + (size_t)(1-p)*3*BHh;

    for (int l = 0; l < 3; ++l) {
      const int K1   = l ? HID : FEAT;
      const int Kper = l ? 256 : 192;
      const int nch  = l ? 4 : 3;
      const unsigned short* A1h = l ? ft_h : (xb_h + p*65536);
      const unsigned short* A1l = l ? ft_l : (xb_l + p*65536);
      const size_t wgo = l ? ((size_t)l*4194304 - 2097152) : 0;

      // ---- gates GEMM + cell ----
      mm_phase<4>(smem, jg << 7, zg*Kper, nch,
                  A1h, A1l, K1,
                  hR_h + (size_t)l*BHh, hR_l + (size_t)l*BHh, HID,
                  Wg_h + wgo, Wg_l + wgo,
                  Whh_h + (size_t)l*4194304, Whh_l + (size_t)l*4194304,
                  gpart + ((size_t)((jg << 3) | zg) << 14));
      sync_tile(fTG, (unsigned)(t*3 + l + 1), b, gpeer0, 32, 8);
      cell_phase(jg, zg, gpart, bsum + (l << 12),
                 l ? ft_h : nullptr, l ? ft_l : nullptr,
                 &cshr[l*512 + tid],
                 hW_h + (size_t)l*BHh, hW_l + (size_t)l*BHh, s_h, s_l);
      sync_grid(fG, ++ggen, b);

      // ---- linear (all 256 WGs) ----
      if (l == 0 && t + 1 < SEQ && tid < 64) {
        // convert x[t+1] into the other xb slot (64 lanes/WG, 16384 float4 total)
        const int u = (b << 6) | tid;
        const float4 v = ((const float4*)x)[(t+1)*16384 + u];
        ushort4 h4, l4;
        h4.x=bf16_rne(v.x); l4.x=bf16_rne(v.x-bf16_tof(h4.x));
        h4.y=bf16_rne(v.y); l4.y=bf16_rne(v.y-bf16_tof(h4.y));
        h4.z=bf16_rne(v.z); l4.z=bf16_rne(v.z-bf16_tof(h4.z));
        h4.w=bf16_rne(v.w); l4.w=bf16_rne(v.w-bf16_tof(h4.w));
        const int q = (t+1) & 1;
        ((ushort4*)(xb_h + q*65536))[u] = h4;
        ((ushort4*)(xb_l + q*65536))[u] = l4;
      }
      mm_phase<2>(smem, jl << 7, zl << 6, 1,
                  s_h + ml*65536, s_l + ml*65536, HID,
                  s_h, s_l, HID,
                  Wout_h, Wout_l, Wout_h, Wout_l,
                  lpart + ((size_t)b << 13));
      sync_tile(fTL, (unsigned)(t*3 + l + 1), b, lpeer0, 1, 16);
      ftred_phase(ml, jl, zl, lpart, bout,
                  (l==2) ? nullptr : ft_h, ft_l,
                  (l==2) ? (out + (size_t)t*BHh) : nullptr);
      sync_grid(fG, ++ggen, b);
    }
  }
}

// ---------------- host ----------------

extern "C" void kernel_launch(void* const* d_in, const int* in_sizes, int n_in,
                              void* d_out, int out_size, void* d_ws, size_t ws_size,
                              hipStream_t stream) {
  const float* x    = (const float*)d_in[0];
  const float* Wih0 = (const float*)d_in[1];
  const float* Wihr = (const float*)d_in[2];
  const float* Whh  = (const float*)d_in[3];
  const float* bih  = (const float*)d_in[4];
  const float* bhh  = (const float*)d_in[5];
  const float* Wout = (const float*)d_in[6];
  const float* bout = (const float*)d_in[7];
  float* out = (float*)d_out;

  char* base = (char*)d_ws;
  size_t off = 0;
  auto alloc = [&](size_t bytes) -> char* {
    char* p = base + off;
    off = (off + bytes + 255) & ~(size_t)255;
    return p;
  };
  float* gpart = (float*)alloc(256ull*16384*4);             // 16.8 MB
  float* lpart = (float*)alloc(256ull*8192*4);              // 8.4 MB
  unsigned short* h_h = (unsigned short*)alloc(2ull*3*BHh*2);
  unsigned short* h_l = (unsigned short*)alloc(2ull*3*BHh*2);
  unsigned short* s_h = (unsigned short*)alloc((size_t)BHh*2);
  unsigned short* s_l = (unsigned short*)alloc((size_t)BHh*2);
  unsigned short* ft_h = (unsigned short*)alloc((size_t)BHh*2);
  unsigned short* ft_l = (unsigned short*)alloc((size_t)BHh*2);
  unsigned short* xb_h = (unsigned short*)alloc(2ull*BATCH*FEAT*2);
  unsigned short* xb_l = (unsigned short*)alloc(2ull*BATCH*FEAT*2);
  float* bsum = (float*)alloc(3ull*G4*4);
  unsigned short* Wg_h  = (unsigned short*)alloc((2097152ull+4194304+4194304)*2);
  unsigned short* Wg_l  = (unsigned short*)alloc((2097152ull+4194304+4194304)*2);
  unsigned short* Whh_h = (unsigned short*)alloc(3ull*4194304*2);
  unsigned short* Whh_l = (unsigned short*)alloc(3ull*4194304*2);
  unsigned short* Wout_h = (unsigned short*)alloc(1048576ull*2);
  unsigned short* Wout_l = (unsigned short*)alloc(1048576ull*2);
  unsigned* fG  = (unsigned*)alloc((size_t)NWG*FLS*4);
  unsigned* fTG = (unsigned*)alloc((size_t)NWG*FLS*4);
  unsigned* fTL = (unsigned*)alloc((size_t)NWG*FLS*4);

  // weight conversion (+ gate-row permutation)
  conv_perm<<<2048, 256, 0, stream>>>(Wih0, Wg_h, Wg_l, G4*FEAT/4, 7);
  conv_perm<<<2048, 256, 0, stream>>>(Wihr,           Wg_h + 2097152, Wg_l + 2097152, G4*HID/4, 8);
  conv_perm<<<2048, 256, 0, stream>>>(Wihr + 4194304, Wg_h + 6291456, Wg_l + 6291456, G4*HID/4, 8);
  for (int l = 0; l < 3; ++l)
    conv_perm<<<2048, 256, 0, stream>>>(Whh + (size_t)l*4194304,
        Whh_h + (size_t)l*4194304, Whh_l + (size_t)l*4194304, G4*HID/4, 8);
  convert_hilo<<<1024, 256, 0, stream>>>(Wout, Wout_h, Wout_l, HID*HID/4);
  bias_perm<<<48, 256, 0, stream>>>(bih, bhh, bsum);

  // zero recurrent state + sync flags each call (replayed in graph)
  hipMemsetAsync(h_h, 0, 2ull*3*BHh*2, stream);
  hipMemsetAsync(h_l, 0, 2ull*3*BHh*2, stream);
  hipMemsetAsync(fG,  0, (size_t)NWG*FLS*4, stream);
  hipMemsetAsync(fTG, 0, (size_t)NWG*FLS*4, stream);
  hipMemsetAsync(fTL, 0, (size_t)NWG*FLS*4, stream);

  fflstm_persist<<<dim3(NWG), dim3(NTHR), 0, stream>>>(
      x, Wg_h, Wg_l, Whh_h, Whh_l, Wout_h, Wout_l, bsum, bout,
      gpart, lpart, h_h, h_l, s_h, s_l, ft_h, ft_l, xb_h, xb_l,
      fG, fTG, fTL, out);
}

// Round 6
// 11964.964 us; speedup vs baseline: 9.7095x; 6.3415x over previous
//
#include <hip/hip_runtime.h>
#include <cmath>

#define SEQ  256
#define BATCH 128
#define FEAT 512
#define HID  1024
#define G4   4096
#define BH (BATCH*HID)

typedef __attribute__((ext_vector_type(8))) __bf16 bf16x8;
typedef __attribute__((ext_vector_type(4))) float f32x4;

__device__ __forceinline__ unsigned short bf16_rne(float f) {
  unsigned int u = __float_as_uint(f);
  unsigned int r = u + 0x7FFFu + ((u >> 16) & 1u);
  return (unsigned short)(r >> 16);
}
__device__ __forceinline__ float bf16_tof(unsigned short s) {
  return __uint_as_float(((unsigned int)s) << 16);
}
__device__ __forceinline__ void gload16(const unsigned short* g, unsigned short* l) {
  __builtin_amdgcn_global_load_lds(
      (const __attribute__((address_space(1))) unsigned int*)g,
      (__attribute__((address_space(3))) unsigned int*)l, 16, 0, 0);
}

// ---------------- conversion kernels (once per call) ----------------

__global__ __launch_bounds__(256)
void convert_hilo(const float* __restrict__ src, unsigned short* __restrict__ hi,
                  unsigned short* __restrict__ lo, int n4) {
  for (int i = blockIdx.x*256 + threadIdx.x; i < n4; i += gridDim.x*256) {
    const float4 v = ((const float4*)src)[i];
    ushort4 h, l;
    h.x = bf16_rne(v.x); l.x = bf16_rne(v.x - bf16_tof(h.x));
    h.y = bf16_rne(v.y); l.y = bf16_rne(v.y - bf16_tof(h.y));
    h.z = bf16_rne(v.z); l.z = bf16_rne(v.z - bf16_tof(h.z));
    h.w = bf16_rne(v.w); l.w = bf16_rne(v.w - bf16_tof(h.w));
    ((ushort4*)hi)[i] = h; ((ushort4*)lo)[i] = l;
  }
}

__global__ __launch_bounds__(256)
void bias_sum(const float* __restrict__ bih, const float* __restrict__ bhh,
              float* __restrict__ bsum) {
  const int i = blockIdx.x*256 + threadIdx.x;
  if (i < 3*G4) bsum[i] = bih[i] + bhh[i];
}

// ---------------- generic split-precision MFMA GEMM core ----------------
// 8 waves as WRN x WCN grid; wave tile (MI*16) x (NI*16); BM = WRN*MI*16,
// BN = WCN*NI*16, BK = 64. 3-product bf16 hi/lo split, fp32 accum.
// Double-buffered LDS + global_load_lds(16B) + XOR-(row&7) swizzle
// (pre-swizzled global source, swizzled ds_read). A = [A1 | A2] rows of
// stride K1 / 1024; W rows n0.. of stride K1 (seg1) / 1024 (seg2).
template<int MI, int NI, int WRN, int WCN>
__device__ __forceinline__ void mm_core(
    unsigned short* lds, int n0, int kstart, int nch,
    const unsigned short* A1h, const unsigned short* A1l, int K1,
    const unsigned short* A2h, const unsigned short* A2l,
    const unsigned short* W1h, const unsigned short* W1l,
    const unsigned short* W2h, const unsigned short* W2l,
    f32x4 acc[MI][NI])
{
  constexpr int AROWS = WRN*MI*16;
  constexpr int WROWS = WCN*NI*16;
  constexpr int OAl = AROWS*64, OWh = 2*AROWS*64, OWl = OWh + WROWS*64;
  constexpr int STRIDE = 2*(AROWS+WROWS)*64;
  constexpr int NLD = (AROWS+WROWS)/32;   // gload16 per wave per chunk
  const int tid = threadIdx.x;
  const int lane = tid & 63, wave = tid >> 6;
  const int wr = wave / WCN, wc = wave % WCN;
  const int rl = lane >> 3, cc = lane & 7;
  const int gcol = (cc ^ rl) << 3;        // pre-swizzled 16B chunk

  auto stage = [&](int ch) {
    const int kg = kstart + (ch << 6);
    const unsigned short *pAh, *pAl, *pWh, *pWl; int sA, sW;
    if (kg < K1) { pAh=A1h+kg; pAl=A1l+kg; sA=K1;   pWh=W1h+kg; pWl=W1l+kg; sW=K1; }
    else { const int k2 = kg - K1;
           pAh=A2h+k2; pAl=A2l+k2; sA=1024; pWh=W2h+k2; pWl=W2l+k2; sW=1024; }
    unsigned short* const db = lds + (ch & 1) * STRIDE;
    #pragma unroll
    for (int q = 0; q < AROWS/64; ++q) {
      const int r0 = wave*(AROWS/8) + q*8;
      const int gr = r0 + rl;
      gload16(pAh + (size_t)gr*sA + gcol, db +       r0*64);
      gload16(pAl + (size_t)gr*sA + gcol, db + OAl + r0*64);
    }
    #pragma unroll
    for (int q = 0; q < WROWS/64; ++q) {
      const int r0 = wave*(WROWS/8) + q*8;
      const int gr = r0 + rl;
      gload16(pWh + (size_t)(n0+gr)*sW + gcol, db + OWh + r0*64);
      gload16(pWl + (size_t)(n0+gr)*sW + gcol, db + OWl + r0*64);
    }
  };

  stage(0);
  for (int ch = 0; ch < nch; ++ch) {
    if (ch + 1 < nch) {
      stage(ch + 1);
      if constexpr (NLD == 8) asm volatile("s_waitcnt vmcnt(8)" ::: "memory");
      else                    asm volatile("s_waitcnt vmcnt(6)" ::: "memory");
    } else {
      asm volatile("s_waitcnt vmcnt(0)" ::: "memory");
    }
    __builtin_amdgcn_sched_barrier(0);
    __builtin_amdgcn_s_barrier();
    const unsigned short* const cb = lds + (ch & 1) * STRIDE;
    #pragma unroll
    for (int kh = 0; kh < 2; ++kh) {
      const int j0 = (kh << 2) + (lane >> 4);
      bf16x8 ah[MI], al[MI], bh[NI], bl[NI];
      #pragma unroll
      for (int mi = 0; mi < MI; ++mi) {
        const int row = wr*(MI*16) + (mi << 4) + (lane & 15);
        const int off = row*64 + ((j0 ^ (row & 7)) << 3);
        ah[mi] = *(const bf16x8*)(cb + off);
        al[mi] = *(const bf16x8*)(cb + OAl + off);
      }
      #pragma unroll
      for (int ni = 0; ni < NI; ++ni) {
        const int wrow = wc*(NI*16) + (ni << 4) + (lane & 15);
        const int off = wrow*64 + ((j0 ^ (wrow & 7)) << 3);
        bh[ni] = *(const bf16x8*)(cb + OWh + off);
        bl[ni] = *(const bf16x8*)(cb + OWl + off);
      }
      #pragma unroll
      for (int mi = 0; mi < MI; ++mi)
        #pragma unroll
        for (int ni = 0; ni < NI; ++ni) {
          acc[mi][ni] = __builtin_amdgcn_mfma_f32_16x16x32_bf16(ah[mi], bh[ni], acc[mi][ni], 0,0,0);
          acc[mi][ni] = __builtin_amdgcn_mfma_f32_16x16x32_bf16(al[mi], bh[ni], acc[mi][ni], 0,0,0);
          acc[mi][ni] = __builtin_amdgcn_mfma_f32_16x16x32_bf16(ah[mi], bl[ni], acc[mi][ni], 0,0,0);
        }
    }
    __builtin_amdgcn_s_barrier();
  }
}

// ---------------- gates GEMM (diagonal-batched, KS=2) ----------------
// grid (32 jt, 2 kz, 3 layer). BM=128 (full batch), BN=128.
// Layer l works on t = d - l; inactive layers return.
__global__ __launch_bounds__(512, 2)
void gates_kernel(int d,
    const unsigned short* __restrict__ xh, const unsigned short* __restrict__ xl,
    const unsigned short* __restrict__ fth, const unsigned short* __restrict__ ftl, // [2][BH]
    const unsigned short* __restrict__ h_h, const unsigned short* __restrict__ h_l, // [2][3][BH]
    const unsigned short* __restrict__ Wg_h, const unsigned short* __restrict__ Wg_l,
    const unsigned short* __restrict__ Whh_h, const unsigned short* __restrict__ Whh_l,
    float* __restrict__ gpart)   // [3][32][2][128*128]
{
  const int l = blockIdx.z;
  const int t = d - l;
  if (t < 0 || t >= SEQ) return;
  const int jt = blockIdx.x, kz = blockIdx.y;
  const int p = d & 1;
  __shared__ unsigned short smem[2*4*128*64];   // 128 KB

  const unsigned short *A1h, *A1l, *W1h, *W1l;
  int K1, Kper;
  if (l == 0) {
    A1h = xh + (size_t)t*BATCH*FEAT; A1l = xl + (size_t)t*BATCH*FEAT;
    K1 = FEAT; Kper = (FEAT+HID)/2;                       // 768
    W1h = Wg_h; W1l = Wg_l;
  } else {
    A1h = fth + (size_t)(l-1)*BH; A1l = ftl + (size_t)(l-1)*BH;
    K1 = HID; Kper = HID;                                  // 1024
    const size_t wo = 2097152ull + (size_t)(l-1)*4194304ull;
    W1h = Wg_h + wo; W1l = Wg_l + wo;
  }
  const unsigned short* A2h = h_h + ((size_t)p*3 + l)*BH;
  const unsigned short* A2l = h_l + ((size_t)p*3 + l)*BH;
  const unsigned short* W2h = Whh_h + (size_t)l*4194304ull;
  const unsigned short* W2l = Whh_l + (size_t)l*4194304ull;

  f32x4 z4 = {0.f,0.f,0.f,0.f};
  f32x4 acc[4][2] = {{z4,z4},{z4,z4},{z4,z4},{z4,z4}};
  mm_core<4,2,2,4>(smem, jt << 7, kz*Kper, Kper >> 6,
                   A1h, A1l, K1, A2h, A2l, W1h, W1l, W2h, W2l, acc);

  // C/D layout: col=lane&15, row=(lane>>4)*4+r  [m89/m91 verified]
  const int lane = threadIdx.x & 63, wave = threadIdx.x >> 6;
  const int wr = wave >> 2, wc = wave & 3;
  const int rb = (lane >> 4) << 2, cbl = lane & 15;
  float* const slab = gpart + ((size_t)((l*32 + jt)*2 + kz) << 14);
  #pragma unroll
  for (int mi = 0; mi < 4; ++mi)
    #pragma unroll
    for (int ni = 0; ni < 2; ++ni)
      #pragma unroll
      for (int r = 0; r < 4; ++r) {
        const int row = (wr << 6) + (mi << 4) + rb + r;
        const int col = (wc << 5) + (ni << 4) + cbl;
        slab[(row << 7) + col] = acc[mi][ni][r];
      }
}

// ---------------- cell (diagonal-batched) ----------------
// grid 768 x 512: e = [0, 3*BH); layer = e>>17.
__global__ __launch_bounds__(512)
void cell_kernel(int d,
    const float* __restrict__ gpart, const float* __restrict__ bsum, // [3][4096]
    const float* __restrict__ ftf,                                   // [2][BH]
    float* __restrict__ c,                                           // [3][BH]
    unsigned short* __restrict__ h_h, unsigned short* __restrict__ h_l, // [2][3][BH]
    unsigned short* __restrict__ s_h, unsigned short* __restrict__ s_l) // [3][BH]
{
  const int e = blockIdx.x*512 + threadIdx.x;
  const int l = e >> 17;
  const int t = d - l;
  if (t < 0 || t >= SEQ) return;
  const int r = e & (BH-1);
  const int m = r >> 10, n = r & 1023;
  float g[4];
  #pragma unroll
  for (int gi = 0; gi < 4; ++gi) {
    const int col = (gi << 10) + n;
    const int jt = col >> 7, c7 = col & 127;
    const float* base = gpart + ((size_t)((l*32 + jt)*2) << 14) + (m << 7) + c7;
    g[gi] = base[0] + base[16384] + bsum[(l << 12) + col];
  }
  const float iv = 1.f/(1.f+expf(-g[0]));
  const float fv = 1.f/(1.f+expf(-g[1]));
  const float gv = tanhf(g[2]);
  const float ov = 1.f/(1.f+expf(-g[3]));
  const float cn = fv * c[e] + iv * gv;
  c[e] = cn;
  const float h = ov * tanhf(cn);
  const int p1 = (d + 1) & 1;                 // parity read by diag d+1
  const size_t hidx = ((size_t)p1*3 + l)*BH + r;
  const unsigned short hh = bf16_rne(h);
  h_h[hidx] = hh; h_l[hidx] = bf16_rne(h - bf16_tof(hh));
  float s = h;
  if (l) s += ftf[(size_t)(l-1)*BH + r];
  const unsigned short ss = bf16_rne(s);
  s_h[(size_t)l*BH + r] = ss;
  s_l[(size_t)l*BH + r] = bf16_rne(s - bf16_tof(ss));
}

// ---------------- linear + reduce fused (KS=1) ----------------
// grid (16 jt, 3 layer). BM=128, BN=64, K=1024. Epilogue adds bout and
// writes ft (f32 + hi/lo) or the final output row-block.
__global__ __launch_bounds__(512, 2)
void lin_kernel(int d,
    const unsigned short* __restrict__ s_h, const unsigned short* __restrict__ s_l,
    const unsigned short* __restrict__ Wout_h, const unsigned short* __restrict__ Wout_l,
    const float* __restrict__ bout,
    float* __restrict__ ftf,
    unsigned short* __restrict__ fth, unsigned short* __restrict__ ftl,
    float* __restrict__ out)
{
  const int l = blockIdx.y;
  const int t = d - l;
  if (t < 0 || t >= SEQ) return;
  const int n0 = blockIdx.x << 6;
  __shared__ unsigned short smem[2*(2*128+2*64)*64];  // 96 KB

  const unsigned short* Ah = s_h + (size_t)l*BH;
  const unsigned short* Al = s_l + (size_t)l*BH;
  f32x4 z4 = {0.f,0.f,0.f,0.f};
  f32x4 acc[2][2] = {{z4,z4},{z4,z4}};
  mm_core<2,2,4,2>(smem, n0, 0, 16,
                   Ah, Al, HID, Ah, Al, Wout_h, Wout_l, Wout_h, Wout_l, acc);

  const int lane = threadIdx.x & 63, wave = threadIdx.x >> 6;
  const int wr = wave >> 1, wc = wave & 1;
  const int rb = (lane >> 4) << 2, cbl = lane & 15;
  #pragma unroll
  for (int mi = 0; mi < 2; ++mi)
    #pragma unroll
    for (int ni = 0; ni < 2; ++ni)
      #pragma unroll
      for (int r = 0; r < 4; ++r) {
        const int row = (wr << 5) + (mi << 4) + rb + r;      // batch m
        const int col = n0 + (wc << 5) + (ni << 4) + cbl;    // hidden n
        const float v = acc[mi][ni][r] + bout[col];
        const size_t idx = ((size_t)row << 10) + col;
        if (l == 2) {
          out[(size_t)t*BH + idx] = v;
        } else {
          ftf[(size_t)l*BH + idx] = v;
          const unsigned short fh = bf16_rne(v);
          fth[(size_t)l*BH + idx] = fh;
          ftl[(size_t)l*BH + idx] = bf16_rne(v - bf16_tof(fh));
        }
      }
}

// ---------------- host ----------------

extern "C" void kernel_launch(void* const* d_in, const int* in_sizes, int n_in,
                              void* d_out, int out_size, void* d_ws, size_t ws_size,
                              hipStream_t stream) {
  const float* x    = (const float*)d_in[0];
  const float* Wih0 = (const float*)d_in[1];
  const float* Wihr = (const float*)d_in[2];
  const float* Whh  = (const float*)d_in[3];
  const float* bih  = (const float*)d_in[4];
  const float* bhh  = (const float*)d_in[5];
  const float* Wout = (const float*)d_in[6];
  const float* bout = (const float*)d_in[7];
  float* out = (float*)d_out;

  char* base = (char*)d_ws;
  size_t off = 0;
  auto alloc = [&](size_t bytes) -> char* {
    char* p = base + off;
    off = (off + bytes + 255) & ~(size_t)255;
    return p;
  };
  float* gpart = (float*)alloc(192ull*16384*4);                 // 12.6 MB
  float* cst   = (float*)alloc(3ull*BH*4);
  float* ftf   = (float*)alloc(2ull*BH*4);
  float* bsum  = (float*)alloc(3ull*G4*4);
  unsigned short* h_h = (unsigned short*)alloc(2ull*3*BH*2);
  unsigned short* h_l = (unsigned short*)alloc(2ull*3*BH*2);
  unsigned short* s_h = (unsigned short*)alloc(3ull*BH*2);
  unsigned short* s_l = (unsigned short*)alloc(3ull*BH*2);
  unsigned short* ft_h = (unsigned short*)alloc(2ull*BH*2);
  unsigned short* ft_l = (unsigned short*)alloc(2ull*BH*2);
  unsigned short* x_h = (unsigned short*)alloc((size_t)SEQ*BATCH*FEAT*2);
  unsigned short* x_l = (unsigned short*)alloc((size_t)SEQ*BATCH*FEAT*2);
  unsigned short* Wg_h  = (unsigned short*)alloc(10485760ull*2); // Wih0 + Wihr(2)
  unsigned short* Wg_l  = (unsigned short*)alloc(10485760ull*2);
  unsigned short* Whh_h = (unsigned short*)alloc(3ull*4194304*2);
  unsigned short* Whh_l = (unsigned short*)alloc(3ull*4194304*2);
  unsigned short* Wout_h = (unsigned short*)alloc(1048576ull*2);
  unsigned short* Wout_l = (unsigned short*)alloc(1048576ull*2);

  // per-call weight + input conversion
  convert_hilo<<<1024, 256, 0, stream>>>(Wih0, Wg_h, Wg_l, G4*FEAT/4);
  convert_hilo<<<2048, 256, 0, stream>>>(Wihr, Wg_h + 2097152, Wg_l + 2097152, 2*G4*HID/4);
  convert_hilo<<<2048, 256, 0, stream>>>(Whh, Whh_h, Whh_l, 3*G4*HID/4);
  convert_hilo<<<1024, 256, 0, stream>>>(Wout, Wout_h, Wout_l, HID*HID/4);
  convert_hilo<<<2048, 256, 0, stream>>>(x, x_h, x_l, SEQ*BATCH*FEAT/4);
  bias_sum<<<48, 256, 0, stream>>>(bih, bhh, bsum);

  // zero recurrent state (both h parities) each call
  hipMemsetAsync(cst, 0, 3ull*BH*4, stream);
  hipMemsetAsync(h_h, 0, 2ull*3*BH*2, stream);
  hipMemsetAsync(h_l, 0, 2ull*3*BH*2, stream);

  const dim3 gGrid(32, 2, 3), lGrid(16, 3);
  for (int d = 0; d < SEQ + 2; ++d) {
    gates_kernel<<<gGrid, 512, 0, stream>>>(d, x_h, x_l, ft_h, ft_l, h_h, h_l,
                                            Wg_h, Wg_l, Whh_h, Whh_l, gpart);
    cell_kernel<<<768, 512, 0, stream>>>(d, gpart, bsum, ftf, cst,
                                         h_h, h_l, s_h, s_l);
    lin_kernel<<<lGrid, 512, 0, stream>>>(d, s_h, s_l, Wout_h, Wout_l, bout,
                                          ftf, ft_h, ft_l, out);
  }
}

// Round 7
// 9068.345 us; speedup vs baseline: 12.8110x; 1.3194x over previous
//
#include <hip/hip_runtime.h>
#include <cmath>

#define SEQ  256
#define BATCH 128
#define FEAT 512
#define HID  1024
#define G4   4096
#define BH (BATCH*HID)

typedef __attribute__((ext_vector_type(8))) _Float16 f16x8;
typedef __attribute__((ext_vector_type(4))) float f32x4;

__device__ __forceinline__ unsigned short f16_rne(float f) {
  _Float16 h = (_Float16)f;
  return __builtin_bit_cast(unsigned short, h);
}
__device__ __forceinline__ float f16_tof(unsigned short s) {
  return (float)__builtin_bit_cast(_Float16, s);
}
__device__ __forceinline__ void gload16(const unsigned short* g, unsigned short* l) {
  __builtin_amdgcn_global_load_lds(
      (const __attribute__((address_space(1))) unsigned int*)g,
      (__attribute__((address_space(3))) unsigned int*)l, 16, 0, 0);
}

// ---------------- conversion kernels (once per call) ----------------

// f32 -> single fp16 (weights)
__global__ __launch_bounds__(256)
void conv16(const float* __restrict__ src, unsigned short* __restrict__ dst, int n4) {
  for (int i = blockIdx.x*256 + threadIdx.x; i < n4; i += gridDim.x*256) {
    const float4 v = ((const float4*)src)[i];
    ushort4 h;
    h.x = f16_rne(v.x); h.y = f16_rne(v.y); h.z = f16_rne(v.z); h.w = f16_rne(v.w);
    ((ushort4*)dst)[i] = h;
  }
}

// f32 -> fp16 hi/lo pair (activations)
__global__ __launch_bounds__(256)
void conv16_hilo(const float* __restrict__ src, unsigned short* __restrict__ hi,
                 unsigned short* __restrict__ lo, int n4) {
  for (int i = blockIdx.x*256 + threadIdx.x; i < n4; i += gridDim.x*256) {
    const float4 v = ((const float4*)src)[i];
    ushort4 h, l;
    h.x = f16_rne(v.x); l.x = f16_rne(v.x - f16_tof(h.x));
    h.y = f16_rne(v.y); l.y = f16_rne(v.y - f16_tof(h.y));
    h.z = f16_rne(v.z); l.z = f16_rne(v.z - f16_tof(h.z));
    h.w = f16_rne(v.w); l.w = f16_rne(v.w - f16_tof(h.w));
    ((ushort4*)hi)[i] = h; ((ushort4*)lo)[i] = l;
  }
}

__global__ __launch_bounds__(256)
void bias_sum(const float* __restrict__ bih, const float* __restrict__ bhh,
              float* __restrict__ bsum) {
  const int i = blockIdx.x*256 + threadIdx.x;
  if (i < 3*G4) bsum[i] = bih[i] + bhh[i];
}

// ---------------- split-precision fp16 MFMA GEMM core ----------------
// 2-product: Ah*W + Al*W (A fp16 hi/lo, W single fp16), fp32 accum.
// 8 waves as WRN x WCN; wave tile (MI*16) x (NI*16); BM=WRN*MI*16=128,
// BN=WCN*NI*16, BK=64. Double-buffered LDS + global_load_lds(16B) +
// XOR-(row&7) swizzle (pre-swizzled global source, swizzled ds_read).
// A = [A1 | A2] (stride K1 / 1024); W rows n0.. (stride K1 / 1024).
template<int MI, int NI, int WRN, int WCN>
__device__ __forceinline__ void mm_core(
    unsigned short* lds, int n0, int kstart, int nch,
    const unsigned short* A1h, const unsigned short* A1l, int K1,
    const unsigned short* A2h, const unsigned short* A2l,
    const unsigned short* W1, const unsigned short* W2,
    f32x4 acc[MI][NI])
{
  constexpr int AROWS = WRN*MI*16;          // 128
  constexpr int WROWS = WCN*NI*16;          // 256 (gates) / 128 (lin)
  constexpr int OAl = AROWS*64;
  constexpr int OW  = 2*AROWS*64;
  constexpr int STRIDE = (2*AROWS + WROWS)*64;
  constexpr int NLD = (2*AROWS + WROWS)/64; // gload16 per wave per chunk (8/6)
  const int tid = threadIdx.x;
  const int lane = tid & 63, wave = tid >> 6;
  const int wr = wave / WCN, wc = wave % WCN;
  const int rl = lane >> 3, cc = lane & 7;
  const int gcol = (cc ^ rl) << 3;          // pre-swizzled 16B chunk

  auto stage = [&](int ch) {
    const int kg = kstart + (ch << 6);
    const unsigned short *pAh, *pAl, *pW; int sA, sW;
    if (kg < K1) { pAh=A1h+kg; pAl=A1l+kg; sA=K1;   pW=W1+kg; sW=K1; }
    else { const int k2 = kg - K1;
           pAh=A2h+k2; pAl=A2l+k2; sA=1024; pW=W2+k2; sW=1024; }
    unsigned short* const db = lds + (ch & 1)*STRIDE;
    #pragma unroll
    for (int q = 0; q < NLD; ++q) {
      const int g = wave*NLD + q;           // 8-row group id, wave-uniform
      if (g < AROWS/8) {
        gload16(pAh + (size_t)(g*8 + rl)*sA + gcol, db + g*512);
      } else if (g < AROWS/4) {
        gload16(pAl + (size_t)((g - AROWS/8)*8 + rl)*sA + gcol, db + g*512);
      } else {
        gload16(pW + (size_t)(n0 + (g - AROWS/4)*8 + rl)*sW + gcol, db + g*512);
      }
    }
  };

  stage(0);
  for (int ch = 0; ch < nch; ++ch) {
    if (ch + 1 < nch) {
      stage(ch + 1);
      if constexpr (NLD == 8) asm volatile("s_waitcnt vmcnt(8)" ::: "memory");
      else                    asm volatile("s_waitcnt vmcnt(6)" ::: "memory");
    } else {
      asm volatile("s_waitcnt vmcnt(0)" ::: "memory");
    }
    __builtin_amdgcn_sched_barrier(0);
    __builtin_amdgcn_s_barrier();
    const unsigned short* const cb = lds + (ch & 1)*STRIDE;
    #pragma unroll
    for (int kh = 0; kh < 2; ++kh) {
      const int j0 = (kh << 2) + (lane >> 4);
      f16x8 ah[MI], al[MI], bh[NI];
      #pragma unroll
      for (int mi = 0; mi < MI; ++mi) {
        const int row = wr*(MI*16) + (mi << 4) + (lane & 15);
        const int off = row*64 + ((j0 ^ (row & 7)) << 3);
        ah[mi] = *(const f16x8*)(cb + off);
        al[mi] = *(const f16x8*)(cb + OAl + off);
      }
      #pragma unroll
      for (int ni = 0; ni < NI; ++ni) {
        const int wrow = wc*(NI*16) + (ni << 4) + (lane & 15);
        const int off = wrow*64 + ((j0 ^ (wrow & 7)) << 3);
        bh[ni] = *(const f16x8*)(cb + OW + off);
      }
      #pragma unroll
      for (int mi = 0; mi < MI; ++mi)
        #pragma unroll
        for (int ni = 0; ni < NI; ++ni) {
          acc[mi][ni] = __builtin_amdgcn_mfma_f32_16x16x32_f16(ah[mi], bh[ni], acc[mi][ni], 0,0,0);
          acc[mi][ni] = __builtin_amdgcn_mfma_f32_16x16x32_f16(al[mi], bh[ni], acc[mi][ni], 0,0,0);
        }
    }
    __builtin_amdgcn_s_barrier();
  }
}

// ---------------- gates GEMM (diagonal-batched, BN=256, KS=4) ----------------
// grid (16 jt, 4 kz, 3 layer), 512 thr. Layer l works on t = d - l.
__global__ __launch_bounds__(512, 2)
void gates_kernel(int d,
    const unsigned short* __restrict__ xh, const unsigned short* __restrict__ xl,
    const unsigned short* __restrict__ fth, const unsigned short* __restrict__ ftl, // [2][BH]
    const unsigned short* __restrict__ h_h, const unsigned short* __restrict__ h_l, // [2][3][BH]
    const unsigned short* __restrict__ Wg,   // fp16: Wih0 | Wihr[0] | Wihr[1]
    const unsigned short* __restrict__ Whh,  // fp16 [3][4096][1024]
    float* __restrict__ gpart)               // [3][16][4][128*256]
{
  const int l = blockIdx.z;
  const int t = d - l;
  if (t < 0 || t >= SEQ) return;
  const int jt = blockIdx.x, kz = blockIdx.y;
  const int p = d & 1;
  __shared__ unsigned short smem[2*(2*128 + 256)*64];   // 128 KB

  const unsigned short *A1h, *A1l, *W1;
  int K1, Kper;
  if (l == 0) {
    A1h = xh + (size_t)t*BATCH*FEAT; A1l = xl + (size_t)t*BATCH*FEAT;
    K1 = FEAT; Kper = (FEAT+HID)/4;                      // 384
    W1 = Wg;
  } else {
    A1h = fth + (size_t)(l-1)*BH; A1l = ftl + (size_t)(l-1)*BH;
    K1 = HID; Kper = (2*HID)/4;                          // 512
    W1 = Wg + 2097152ull + (size_t)(l-1)*4194304ull;
  }
  const unsigned short* A2h = h_h + ((size_t)p*3 + l)*BH;
  const unsigned short* A2l = h_l + ((size_t)p*3 + l)*BH;
  const unsigned short* W2  = Whh + (size_t)l*4194304ull;

  f32x4 z4 = {0.f,0.f,0.f,0.f};
  f32x4 acc[4][4];
  #pragma unroll
  for (int a = 0; a < 4; ++a) { acc[a][0]=z4; acc[a][1]=z4; acc[a][2]=z4; acc[a][3]=z4; }
  mm_core<4,4,2,4>(smem, jt << 8, kz*Kper, Kper >> 6,
                   A1h, A1l, K1, A2h, A2l, W1, W2, acc);

  // C/D layout: col=lane&15, row=(lane>>4)*4+r  [m89/m91 verified]
  const int lane = threadIdx.x & 63, wave = threadIdx.x >> 6;
  const int wr = wave >> 2, wc = wave & 3;
  const int rb = (lane >> 4) << 2, cbl = lane & 15;
  float* const slab = gpart + ((size_t)((l*16 + jt)*4 + kz) << 15);
  #pragma unroll
  for (int mi = 0; mi < 4; ++mi)
    #pragma unroll
    for (int ni = 0; ni < 4; ++ni)
      #pragma unroll
      for (int r = 0; r < 4; ++r) {
        const int row = (wr << 6) + (mi << 4) + rb + r;
        const int col = (wc << 6) + (ni << 4) + cbl;
        slab[(row << 8) + col] = acc[mi][ni][r];
      }
}

// ---------------- cell (diagonal-batched) ----------------
// grid 768 x 512: e in [0, 3*BH); layer = e>>17.
__global__ __launch_bounds__(512)
void cell_kernel(int d,
    const float* __restrict__ gpart, const float* __restrict__ bsum, // [3][4096]
    const float* __restrict__ ftf,                                   // [2][BH]
    float* __restrict__ c,                                           // [3][BH]
    unsigned short* __restrict__ h_h, unsigned short* __restrict__ h_l, // [2][3][BH]
    unsigned short* __restrict__ s_h, unsigned short* __restrict__ s_l) // [3][BH]
{
  const int e = blockIdx.x*512 + threadIdx.x;
  const int l = e >> 17;
  const int t = d - l;
  if (t < 0 || t >= SEQ) return;
  const int r = e & (BH-1);
  const int m = r >> 10, n = r & 1023;
  float g[4];
  #pragma unroll
  for (int gi = 0; gi < 4; ++gi) {
    const int col = (gi << 10) + n;
    const int jt = col >> 8, c8 = col & 255;
    const float* base = gpart + ((size_t)((l*16 + jt)*4) << 15) + (m << 8) + c8;
    g[gi] = base[0] + base[1u<<15] + base[2u<<15] + base[3u<<15]
          + bsum[(l << 12) + col];
  }
  const float iv = 1.f/(1.f+expf(-g[0]));
  const float fv = 1.f/(1.f+expf(-g[1]));
  const float gv = tanhf(g[2]);
  const float ov = 1.f/(1.f+expf(-g[3]));
  const float cn = fv * c[e] + iv * gv;
  c[e] = cn;
  const float h = ov * tanhf(cn);
  const int p1 = (d + 1) & 1;                 // parity read by diag d+1
  const size_t hidx = ((size_t)p1*3 + l)*BH + r;
  const unsigned short hh = f16_rne(h);
  h_h[hidx] = hh; h_l[hidx] = f16_rne(h - f16_tof(hh));
  float s = h;
  if (l) s += ftf[(size_t)(l-1)*BH + r];
  const unsigned short ss = f16_rne(s);
  s_h[(size_t)l*BH + r] = ss;
  s_l[(size_t)l*BH + r] = f16_rne(s - f16_tof(ss));
}

// ---------------- output linear (BN=128, KS=4) ----------------
// grid (8 jt, 4 kz, 3 layer).
__global__ __launch_bounds__(512, 2)
void lin_kernel(int d,
    const unsigned short* __restrict__ s_h, const unsigned short* __restrict__ s_l,
    const unsigned short* __restrict__ Wout,  // fp16 [1024][1024]
    float* __restrict__ lpart)                // [3][8][4][128*128]
{
  const int l = blockIdx.z;
  const int t = d - l;
  if (t < 0 || t >= SEQ) return;
  const int jt = blockIdx.x, kz = blockIdx.y;
  __shared__ unsigned short smem[2*(2*128 + 128)*64];   // 96 KB

  const unsigned short* Ah = s_h + (size_t)l*BH;
  const unsigned short* Al = s_l + (size_t)l*BH;
  f32x4 z4 = {0.f,0.f,0.f,0.f};
  f32x4 acc[4][2];
  #pragma unroll
  for (int a = 0; a < 4; ++a) { acc[a][0]=z4; acc[a][1]=z4; }
  mm_core<4,2,2,4>(smem, jt << 7, kz << 8, 4,
                   Ah, Al, HID, Ah, Al, Wout, Wout, acc);

  const int lane = threadIdx.x & 63, wave = threadIdx.x >> 6;
  const int wr = wave >> 2, wc = wave & 3;
  const int rb = (lane >> 4) << 2, cbl = lane & 15;
  float* const slab = lpart + ((size_t)((l*8 + jt)*4 + kz) << 14);
  #pragma unroll
  for (int mi = 0; mi < 4; ++mi)
    #pragma unroll
    for (int ni = 0; ni < 2; ++ni)
      #pragma unroll
      for (int r = 0; r < 4; ++r) {
        const int row = (wr << 6) + (mi << 4) + rb + r;
        const int col = (wc << 5) + (ni << 4) + cbl;
        slab[(row << 7) + col] = acc[mi][ni][r];
      }
}

// ---------------- linear reduce + bias -> ft / out ----------------
__global__ __launch_bounds__(512)
void linred_kernel(int d,
    const float* __restrict__ lpart, const float* __restrict__ bout,
    float* __restrict__ ftf,
    unsigned short* __restrict__ fth, unsigned short* __restrict__ ftl,
    float* __restrict__ out)
{
  const int e = blockIdx.x*512 + threadIdx.x;
  const int l = e >> 17;
  const int t = d - l;
  if (t < 0 || t >= SEQ) return;
  const int r = e & (BH-1);
  const int m = r >> 10, n = r & 1023;
  const int jt = n >> 7, c7 = n & 127;
  const float* base = lpart + ((size_t)((l*8 + jt)*4) << 14) + (m << 7) + c7;
  float v = bout[n] + base[0] + base[1u<<14] + base[2u<<14] + base[3u<<14];
  if (l == 2) {
    out[(size_t)t*BH + r] = v;
  } else {
    ftf[(size_t)l*BH + r] = v;
    const unsigned short fh = f16_rne(v);
    fth[(size_t)l*BH + r] = fh;
    ftl[(size_t)l*BH + r] = f16_rne(v - f16_tof(fh));
  }
}

// ---------------- host ----------------

extern "C" void kernel_launch(void* const* d_in, const int* in_sizes, int n_in,
                              void* d_out, int out_size, void* d_ws, size_t ws_size,
                              hipStream_t stream) {
  const float* x    = (const float*)d_in[0];
  const float* Wih0 = (const float*)d_in[1];
  const float* Wihr = (const float*)d_in[2];
  const float* Whh  = (const float*)d_in[3];
  const float* bih  = (const float*)d_in[4];
  const float* bhh  = (const float*)d_in[5];
  const float* Wout = (const float*)d_in[6];
  const float* bout = (const float*)d_in[7];
  float* out = (float*)d_out;

  char* base = (char*)d_ws;
  size_t off = 0;
  auto alloc = [&](size_t bytes) -> char* {
    char* p = base + off;
    off = (off + bytes + 255) & ~(size_t)255;
    return p;
  };
  float* gpart = (float*)alloc(192ull*32768*4);                  // 25.2 MB
  float* lpart = (float*)alloc(96ull*16384*4);                   // 6.3 MB
  float* cst   = (float*)alloc(3ull*BH*4);
  float* ftf   = (float*)alloc(2ull*BH*4);
  float* bsum  = (float*)alloc(3ull*G4*4);
  unsigned short* h_h = (unsigned short*)alloc(2ull*3*BH*2);
  unsigned short* h_l = (unsigned short*)alloc(2ull*3*BH*2);
  unsigned short* s_h = (unsigned short*)alloc(3ull*BH*2);
  unsigned short* s_l = (unsigned short*)alloc(3ull*BH*2);
  unsigned short* ft_h = (unsigned short*)alloc(2ull*BH*2);
  unsigned short* ft_l = (unsigned short*)alloc(2ull*BH*2);
  unsigned short* x_h = (unsigned short*)alloc((size_t)SEQ*BATCH*FEAT*2);
  unsigned short* x_l = (unsigned short*)alloc((size_t)SEQ*BATCH*FEAT*2);
  unsigned short* WgC   = (unsigned short*)alloc(10485760ull*2); // Wih0 + Wihr
  unsigned short* WhhC  = (unsigned short*)alloc(3ull*4194304*2);
  unsigned short* WoutC = (unsigned short*)alloc(1048576ull*2);

  // per-call conversions: weights -> fp16 single, x -> fp16 hi/lo
  conv16<<<1024, 256, 0, stream>>>(Wih0, WgC, G4*FEAT/4);
  conv16<<<2048, 256, 0, stream>>>(Wihr, WgC + 2097152, 2*G4*HID/4);
  conv16<<<2048, 256, 0, stream>>>(Whh,  WhhC, 3*G4*HID/4);
  conv16<<<1024, 256, 0, stream>>>(Wout, WoutC, HID*HID/4);
  conv16_hilo<<<2048, 256, 0, stream>>>(x, x_h, x_l, SEQ*BATCH*FEAT/4);
  bias_sum<<<48, 256, 0, stream>>>(bih, bhh, bsum);

  // zero recurrent state (both h parities) each call
  hipMemsetAsync(cst, 0, 3ull*BH*4, stream);
  hipMemsetAsync(h_h, 0, 2ull*3*BH*2, stream);
  hipMemsetAsync(h_l, 0, 2ull*3*BH*2, stream);

  const dim3 gGrid(16, 4, 3), lGrid(8, 4, 3);
  for (int d = 0; d < SEQ + 2; ++d) {
    gates_kernel<<<gGrid, 512, 0, stream>>>(d, x_h, x_l, ft_h, ft_l, h_h, h_l,
                                            WgC, WhhC, gpart);
    cell_kernel<<<768, 512, 0, stream>>>(d, gpart, bsum, ftf, cst,
                                         h_h, h_l, s_h, s_l);
    lin_kernel<<<lGrid, 512, 0, stream>>>(d, s_h, s_l, WoutC, lpart);
    linred_kernel<<<768, 512, 0, stream>>>(d, lpart, bout, ftf, ft_h, ft_l, out);
  }
}

// Round 8
// 6717.779 us; speedup vs baseline: 17.2936x; 1.3499x over previous
//
#include <hip/hip_runtime.h>
#include <cmath>

#define SEQ  256
#define BATCH 128
#define FEAT 512
#define HID  1024
#define G4   4096
#define BH (BATCH*HID)

typedef __attribute__((ext_vector_type(8))) _Float16 f16x8;
typedef __attribute__((ext_vector_type(4))) float f32x4;

__device__ __forceinline__ unsigned short f16_rne(float f) {
  _Float16 h = (_Float16)f;
  return __builtin_bit_cast(unsigned short, h);
}
__device__ __forceinline__ float f16_tof(unsigned short s) {
  return (float)__builtin_bit_cast(_Float16, s);
}
__device__ __forceinline__ void gload16(const unsigned short* g, unsigned short* l) {
  __builtin_amdgcn_global_load_lds(
      (const __attribute__((address_space(1))) unsigned int*)g,
      (__attribute__((address_space(3))) unsigned int*)l, 16, 0, 0);
}

// ---------------- one-time conversion kernels ----------------

__global__ __launch_bounds__(256)
void conv16(const float* __restrict__ src, unsigned short* __restrict__ dst, int n4) {
  for (int i = blockIdx.x*256 + threadIdx.x; i < n4; i += gridDim.x*256) {
    const float4 v = ((const float4*)src)[i];
    ushort4 h;
    h.x = f16_rne(v.x); h.y = f16_rne(v.y); h.z = f16_rne(v.z); h.w = f16_rne(v.w);
    ((ushort4*)dst)[i] = h;
  }
}

__global__ __launch_bounds__(256)
void conv16_hilo(const float* __restrict__ src, unsigned short* __restrict__ hi,
                 unsigned short* __restrict__ lo, int n4) {
  for (int i = blockIdx.x*256 + threadIdx.x; i < n4; i += gridDim.x*256) {
    const float4 v = ((const float4*)src)[i];
    ushort4 h, l;
    h.x = f16_rne(v.x); l.x = f16_rne(v.x - f16_tof(h.x));
    h.y = f16_rne(v.y); l.y = f16_rne(v.y - f16_tof(h.y));
    h.z = f16_rne(v.z); l.z = f16_rne(v.z - f16_tof(h.z));
    h.w = f16_rne(v.w); l.w = f16_rne(v.w - f16_tof(h.w));
    ((ushort4*)hi)[i] = h; ((ushort4*)lo)[i] = l;
  }
}

// WoutT[c][k] = f16(Wout[k][c])
__global__ __launch_bounds__(256)
void transp16(const float* __restrict__ src, unsigned short* __restrict__ dst) {
  const int i = blockIdx.x*256 + threadIdx.x;   // 1M
  const int k = i >> 10, c = i & 1023;
  dst[(c << 10) + k] = f16_rne(src[i]);
}

__global__ __launch_bounds__(256)
void bias_sum(const float* __restrict__ bih, const float* __restrict__ bhh,
              float* __restrict__ bsum) {
  const int i = blockIdx.x*256 + threadIdx.x;
  if (i < 3*G4) bsum[i] = bih[i] + bhh[i];
}

// bsum[l][r] += Wihr[l-1][r][:] . bout   for l in {1,2}
__global__ __launch_bounds__(256)
void bias2_gemv(const float* __restrict__ Wihr, const float* __restrict__ bout,
                float* __restrict__ bsum) {
  const int u = blockIdx.x*256 + threadIdx.x;   // 0..8191
  if (u >= 2*G4) return;
  const int l = 1 + (u >> 12), r = u & 4095;
  const float* wrow = Wihr + ((size_t)(l-1)*G4 + r)*HID;
  float acc = 0.f;
  for (int k4 = 0; k4 < HID/4; ++k4) {
    const float4 w = ((const float4*)wrow)[k4];
    const float4 b = ((const float4*)bout)[k4];
    acc += w.x*b.x + w.y*b.y + w.z*b.z + w.w*b.w;
  }
  bsum[(l << 12) + r] += acc;
}

// ---------------- split-precision fp16 MFMA GEMM core (round-7 verified) ----
// P2: Ah*W + Al*W (A fp16 hi/lo); !P2: Ah*W only.
// 8 waves as WRN x WCN; wave tile (MI*16) x (NI*16); BM=WRN*MI*16=128,
// BN=WCN*NI*16, BK=64. Double-buffered LDS + global_load_lds(16B) +
// XOR-(row&7) swizzle. A = [A1 | A2] (stride K1 / 1024); W rows n0..
// (stride K1 seg1 / 1024 seg2).
template<int MI, int NI, int WRN, int WCN, bool P2>
__device__ __forceinline__ void mm_core(
    unsigned short* lds, int n0, int kstart, int nch,
    const unsigned short* A1h, const unsigned short* A1l, int K1,
    const unsigned short* A2h, const unsigned short* A2l,
    const unsigned short* W1, const unsigned short* W2,
    f32x4 acc[MI][NI])
{
  constexpr int AROWS = WRN*MI*16;          // 128
  constexpr int WROWS = WCN*NI*16;          // 256 or 128
  constexpr int OAl = AROWS*64;
  constexpr int OW  = 2*AROWS*64;
  constexpr int STRIDE = (2*AROWS + WROWS)*64;
  constexpr int NLD = (2*AROWS + WROWS)/64; // 8 or 6
  const int tid = threadIdx.x;
  const int lane = tid & 63, wave = tid >> 6;
  const int wr = wave / WCN, wc = wave % WCN;
  const int rl = lane >> 3, cc = lane & 7;
  const int gcol = (cc ^ rl) << 3;

  auto stage = [&](int ch) {
    const int kg = kstart + (ch << 6);
    const unsigned short *pAh, *pAl, *pW; int sA, sW;
    if (kg < K1) { pAh=A1h+kg; pAl=A1l+kg; sA=K1;   pW=W1+kg; sW=K1; }
    else { const int k2 = kg - K1;
           pAh=A2h+k2; pAl=A2l+k2; sA=1024; pW=W2+k2; sW=1024; }
    unsigned short* const db = lds + (ch & 1)*STRIDE;
    #pragma unroll
    for (int q = 0; q < NLD; ++q) {
      const int g = wave*NLD + q;           // 8-row group id, wave-uniform
      if (g < AROWS/8) {
        gload16(pAh + (size_t)(g*8 + rl)*sA + gcol, db + g*512);
      } else if (g < AROWS/4) {
        gload16(pAl + (size_t)((g - AROWS/8)*8 + rl)*sA + gcol, db + g*512);
      } else {
        gload16(pW + (size_t)(n0 + (g - AROWS/4)*8 + rl)*sW + gcol, db + g*512);
      }
    }
  };

  stage(0);
  for (int ch = 0; ch < nch; ++ch) {
    if (ch + 1 < nch) {
      stage(ch + 1);
      if constexpr (NLD == 8) asm volatile("s_waitcnt vmcnt(8)" ::: "memory");
      else                    asm volatile("s_waitcnt vmcnt(6)" ::: "memory");
    } else {
      asm volatile("s_waitcnt vmcnt(0)" ::: "memory");
    }
    __builtin_amdgcn_sched_barrier(0);
    __builtin_amdgcn_s_barrier();
    const unsigned short* const cb = lds + (ch & 1)*STRIDE;
    #pragma unroll
    for (int kh = 0; kh < 2; ++kh) {
      const int j0 = (kh << 2) + (lane >> 4);
      f16x8 ah[MI], al[MI], bh[NI];
      #pragma unroll
      for (int mi = 0; mi < MI; ++mi) {
        const int row = wr*(MI*16) + (mi << 4) + (lane & 15);
        const int off = row*64 + ((j0 ^ (row & 7)) << 3);
        ah[mi] = *(const f16x8*)(cb + off);
        if constexpr (P2) al[mi] = *(const f16x8*)(cb + OAl + off);
      }
      #pragma unroll
      for (int ni = 0; ni < NI; ++ni) {
        const int wrow = wc*(NI*16) + (ni << 4) + (lane & 15);
        const int off = wrow*64 + ((j0 ^ (wrow & 7)) << 3);
        bh[ni] = *(const f16x8*)(cb + OW + off);
      }
      #pragma unroll
      for (int mi = 0; mi < MI; ++mi)
        #pragma unroll
        for (int ni = 0; ni < NI; ++ni) {
          acc[mi][ni] = __builtin_amdgcn_mfma_f32_16x16x32_f16(ah[mi], bh[ni], acc[mi][ni], 0,0,0);
          if constexpr (P2)
            acc[mi][ni] = __builtin_amdgcn_mfma_f32_16x16x32_f16(al[mi], bh[ni], acc[mi][ni], 0,0,0);
        }
    }
    __builtin_amdgcn_s_barrier();
  }
}

// ---------------- Wfused = Wihr @ Wout (once per call) ----------------
// grid (32 mb, 4 jt, 2 z). A = WrC[z] rows mb*128.., W = WoutT rows jt*256..
__global__ __launch_bounds__(512, 2)
void wfuse_kernel(const unsigned short* __restrict__ WrC,
                  const unsigned short* __restrict__ WoutT,
                  unsigned short* __restrict__ Wfused)
{
  __shared__ unsigned short smem[2*(2*128 + 256)*64];   // 128 KB
  const int mb = blockIdx.x, jt = blockIdx.y, z = blockIdx.z;
  const unsigned short* A = WrC + ((size_t)z*G4 + mb*128)*HID;
  f32x4 z4 = {0.f,0.f,0.f,0.f};
  f32x4 acc[4][4];
  #pragma unroll
  for (int a = 0; a < 4; ++a) { acc[a][0]=z4; acc[a][1]=z4; acc[a][2]=z4; acc[a][3]=z4; }
  mm_core<4,4,2,4,false>(smem, jt << 8, 0, 16, A, A, HID, A, A, WoutT, WoutT, acc);

  const int lane = threadIdx.x & 63, wave = threadIdx.x >> 6;
  const int wr = wave >> 2, wc = wave & 3;
  const int rb = (lane >> 4) << 2, cbl = lane & 15;
  unsigned short* const dst = Wfused + (size_t)z*G4*HID;
  #pragma unroll
  for (int mi = 0; mi < 4; ++mi)
    #pragma unroll
    for (int ni = 0; ni < 4; ++ni)
      #pragma unroll
      for (int r = 0; r < 4; ++r) {
        const int row = mb*128 + (wr << 6) + (mi << 4) + rb + r;
        const int col = (jt << 8) + (wc << 6) + (ni << 4) + cbl;
        dst[((size_t)row << 10) + col] = f16_rne(acc[mi][ni][r]);
      }
}

// ---------------- launch 1: all GEMMs of diagonal d ----------------
// 240 blocks: [0,64)   l=0 gates (16 jt x 4 kz), N=4096, K=1536
//             [64,208) l=1,2: 72 each = 16 jt x 4 kz normal (Wfused|Whh)
//                              + 4 jt x 2 kz extended (Wout, s-half only)
//             [208,240) out-lin: s(2)@Wout, 8 jt x 4 kz, BN=128
__global__ __launch_bounds__(512, 2)
void gemm_diag(int d,
    const unsigned short* __restrict__ xh, const unsigned short* __restrict__ xl,
    const unsigned short* __restrict__ s_h, const unsigned short* __restrict__ s_l,
    const unsigned short* __restrict__ h_h, const unsigned short* __restrict__ h_l,
    const unsigned short* __restrict__ Wih0C, const unsigned short* __restrict__ WfusedC,
    const unsigned short* __restrict__ WhhC,  const unsigned short* __restrict__ WoutC,
    float* __restrict__ gpart,   // [3][20][4][128*256]
    float* __restrict__ lpart)   // [8][4][128*128]
{
  __shared__ unsigned short smem[2*(2*128 + 256)*64];   // 128 KB
  const int bid = blockIdx.x;
  const int p = d & 1;
  const int lane = threadIdx.x & 63, wave = threadIdx.x >> 6;
  const int rb = (lane >> 4) << 2, cbl = lane & 15;

  if (bid < 208) {
    int l, jt, kz, nch, kstart, n0w, K1;
    const unsigned short *A1h_, *A1l_, *W1;
    if (bid < 64) {
      l = 0; jt = bid >> 2; kz = bid & 3;
      const int t = d;
      if (t >= SEQ) return;
      A1h_ = xh + (size_t)t*BATCH*FEAT; A1l_ = xl + (size_t)t*BATCH*FEAT;
      K1 = FEAT; kstart = kz*384; nch = 6;
      W1 = Wih0C; n0w = jt << 8;
    } else {
      int u = bid - 64;
      l = 1 + u/72; u %= 72;
      const int t = d - l;
      if (t < 0 || t >= SEQ) return;
      A1h_ = s_h + (size_t)(l-1)*BH; A1l_ = s_l + (size_t)(l-1)*BH;
      K1 = HID; kstart = 0; nch = 8;
      if (u < 64) {
        jt = u >> 2; kz = u & 3;
        W1 = WfusedC + (size_t)(l-1)*G4*HID; n0w = jt << 8;
      } else {
        const int w = u - 64;                 // 0..7
        jt = 16 + (w >> 1); kz = w & 1;       // s-half only
        W1 = WoutC; n0w = (jt - 16) << 8;
      }
      kstart = kz*512;
    }
    const unsigned short* A2h_ = h_h + ((size_t)p*3 + l)*BH;
    const unsigned short* A2l_ = h_l + ((size_t)p*3 + l)*BH;
    const unsigned short* W2 = WhhC + (size_t)l*G4*HID;

    f32x4 z4 = {0.f,0.f,0.f,0.f};
    f32x4 acc[4][4];
    #pragma unroll
    for (int a = 0; a < 4; ++a) { acc[a][0]=z4; acc[a][1]=z4; acc[a][2]=z4; acc[a][3]=z4; }
    mm_core<4,4,2,4,true>(smem, n0w, kstart, nch, A1h_, A1l_, K1, A2h_, A2l_, W1, W2, acc);

    // C/D layout: col=lane&15, row=(lane>>4)*4+r  [m89/m91 verified]
    const int wr = wave >> 2, wc = wave & 3;
    float* const slab = gpart + ((size_t)((l*20 + jt)*4 + kz) << 15);
    #pragma unroll
    for (int mi = 0; mi < 4; ++mi)
      #pragma unroll
      for (int ni = 0; ni < 4; ++ni)
        #pragma unroll
        for (int r = 0; r < 4; ++r) {
          const int row = (wr << 6) + (mi << 4) + rb + r;
          const int col = (wc << 6) + (ni << 4) + cbl;
          slab[(row << 8) + col] = acc[mi][ni][r];
        }
  } else {
    // out-lin: lpart = s(2) @ Wout^T
    const int u = bid - 208;
    const int t = d - 3;
    if (t < 0 || t >= SEQ) return;
    const int jt = u >> 2, kz = u & 3;
    const unsigned short* Ah = s_h + (size_t)2*BH;
    const unsigned short* Al = s_l + (size_t)2*BH;
    f32x4 z4 = {0.f,0.f,0.f,0.f};
    f32x4 acc[2][4];
    #pragma unroll
    for (int a = 0; a < 2; ++a) { acc[a][0]=z4; acc[a][1]=z4; acc[a][2]=z4; acc[a][3]=z4; }
    mm_core<2,4,4,2,true>(smem, jt << 7, kz << 8, 4, Ah, Al, HID, Ah, Al, WoutC, WoutC, acc);

    const int wr = wave >> 1, wc = wave & 1;    // WRN=4, WCN=2
    float* const slab = lpart + ((size_t)(jt*4 + kz) << 14);
    #pragma unroll
    for (int mi = 0; mi < 2; ++mi)
      #pragma unroll
      for (int ni = 0; ni < 4; ++ni)
        #pragma unroll
        for (int r = 0; r < 4; ++r) {
          const int row = (wr << 5) + (mi << 4) + rb + r;
          const int col = (wc << 6) + (ni << 4) + cbl;
          slab[(row << 7) + col] = acc[mi][ni][r];
        }
  }
}

// ---------------- launch 2: cell + ft + out of diagonal d ----------------
// 1024 blocks x 512: [0,768) cell (3 layers x BH), [768,1024) out (BH).
__global__ __launch_bounds__(512)
void cell_diag(int d,
    const float* __restrict__ gpart, const float* __restrict__ lpart,
    const float* __restrict__ bias2, const float* __restrict__ bout,
    float* __restrict__ c,
    unsigned short* __restrict__ h_h, unsigned short* __restrict__ h_l,
    unsigned short* __restrict__ s_h, unsigned short* __restrict__ s_l,
    float* __restrict__ out)
{
  const int bid = blockIdx.x;
  if (bid < 768) {
    const int e = bid*512 + threadIdx.x;
    const int l = e >> 17;
    const int t = d - l;
    if (t < 0 || t >= SEQ) return;
    const int r = e & (BH-1);
    const int m = r >> 10, n = r & 1023;
    float g[4];
    #pragma unroll
    for (int gi = 0; gi < 4; ++gi) {
      const int col = (gi << 10) + n;
      const int jt = col >> 8, c8 = col & 255;
      const float* base = gpart + ((size_t)((l*20 + jt)*4) << 15) + (m << 8) + c8;
      g[gi] = base[0] + base[1u<<15] + base[2u<<15] + base[3u<<15]
            + bias2[(l << 12) + col];
    }
    const float iv = 1.f/(1.f+expf(-g[0]));
    const float fv = 1.f/(1.f+expf(-g[1]));
    const float gv = tanhf(g[2]);
    const float ov = 1.f/(1.f+expf(-g[3]));
    const float cn = fv * c[e] + iv * gv;
    c[e] = cn;
    const float h = ov * tanhf(cn);
    const int p1 = (d + 1) & 1;
    const size_t hidx = ((size_t)p1*3 + l)*BH + r;
    const unsigned short hh = f16_rne(h);
    h_h[hidx] = hh; h_l[hidx] = f16_rne(h - f16_tof(hh));
    float s = h;
    if (l) {
      // ft(l-1) = bout + extended-tile partials (s-half kz 0,1)
      const int jtf = 16 + (n >> 8);
      const float* bf = gpart + ((size_t)((l*20 + jtf)*4) << 15) + (m << 8) + (n & 255);
      s += bout[n] + bf[0] + bf[1u<<15];
    }
    const unsigned short ss = f16_rne(s);
    s_h[(size_t)l*BH + r] = ss;
    s_l[(size_t)l*BH + r] = f16_rne(s - f16_tof(ss));
  } else {
    const int t = d - 3;
    if (t < 0 || t >= SEQ) return;
    const int e = (bid - 768)*512 + threadIdx.x;   // 0..BH
    const int m = e >> 10, n = e & 1023;
    const float* base = lpart + ((size_t)((n >> 7)*4) << 14) + (m << 7) + (n & 127);
    out[(size_t)t*BH + e] = bout[n]
        + base[0] + base[1u<<14] + base[2u<<14] + base[3u<<14];
  }
}

// ---------------- host ----------------

extern "C" void kernel_launch(void* const* d_in, const int* in_sizes, int n_in,
                              void* d_out, int out_size, void* d_ws, size_t ws_size,
                              hipStream_t stream) {
  const float* x    = (const float*)d_in[0];
  const float* Wih0 = (const float*)d_in[1];
  const float* Wihr = (const float*)d_in[2];
  const float* Whh  = (const float*)d_in[3];
  const float* bih  = (const float*)d_in[4];
  const float* bhh  = (const float*)d_in[5];
  const float* Wout = (const float*)d_in[6];
  const float* bout = (const float*)d_in[7];
  float* out = (float*)d_out;

  char* base = (char*)d_ws;
  size_t off = 0;
  auto alloc = [&](size_t bytes) -> char* {
    char* p = base + off;
    off = (off + bytes + 255) & ~(size_t)255;
    return p;
  };
  float* gpart = (float*)alloc(3ull*20*4*32768*4);               // 31.5 MB
  float* lpart = (float*)alloc(8ull*4*16384*4);                  // 2.1 MB
  float* cst   = (float*)alloc(3ull*BH*4);
  float* bsum  = (float*)alloc(3ull*G4*4);
  unsigned short* h_h = (unsigned short*)alloc(2ull*3*BH*2);
  unsigned short* h_l = (unsigned short*)alloc(2ull*3*BH*2);
  unsigned short* s_h = (unsigned short*)alloc(3ull*BH*2);
  unsigned short* s_l = (unsigned short*)alloc(3ull*BH*2);
  unsigned short* x_h = (unsigned short*)alloc((size_t)SEQ*BATCH*FEAT*2);
  unsigned short* x_l = (unsigned short*)alloc((size_t)SEQ*BATCH*FEAT*2);
  unsigned short* Wih0C  = (unsigned short*)alloc((size_t)G4*FEAT*2);
  unsigned short* WhhC   = (unsigned short*)alloc(3ull*G4*HID*2);
  unsigned short* WoutC  = (unsigned short*)alloc((size_t)HID*HID*2);
  unsigned short* WoutT  = (unsigned short*)alloc((size_t)HID*HID*2);
  unsigned short* WfusedC= (unsigned short*)alloc(2ull*G4*HID*2); // 16.8 MB
  // Wihr f16 staging aliases gpart (used only before the main loop)
  unsigned short* WrC = (unsigned short*)gpart;                   // 16.8 MB <= 31.5

  // one-time conversions
  conv16<<<1024, 256, 0, stream>>>(Wih0, Wih0C, G4*FEAT/4);
  conv16<<<2048, 256, 0, stream>>>(Whh,  WhhC,  3*G4*HID/4);
  conv16<<<1024, 256, 0, stream>>>(Wout, WoutC, HID*HID/4);
  transp16<<<4096, 256, 0, stream>>>(Wout, WoutT);
  conv16<<<2048, 256, 0, stream>>>(Wihr, WrC, 2*G4*HID/4);
  conv16_hilo<<<2048, 256, 0, stream>>>(x, x_h, x_l, SEQ*BATCH*FEAT/4);
  bias_sum<<<48, 256, 0, stream>>>(bih, bhh, bsum);
  bias2_gemv<<<32, 256, 0, stream>>>(Wihr, bout, bsum);
  wfuse_kernel<<<dim3(32, 4, 2), 512, 0, stream>>>(WrC, WoutT, WfusedC);

  // zero recurrent state each call
  hipMemsetAsync(cst, 0, 3ull*BH*4, stream);
  hipMemsetAsync(h_h, 0, 2ull*3*BH*2, stream);
  hipMemsetAsync(h_l, 0, 2ull*3*BH*2, stream);

  for (int d = 0; d < SEQ + 3; ++d) {
    gemm_diag<<<240, 512, 0, stream>>>(d, x_h, x_l, s_h, s_l, h_h, h_l,
                                       Wih0C, WfusedC, WhhC, WoutC, gpart, lpart);
    cell_diag<<<1024, 512, 0, stream>>>(d, gpart, lpart, bsum, bout, cst,
                                        h_h, h_l, s_h, s_l, out);
  }
}